// Round 7
// baseline (412.949 us; speedup 1.0000x reference)
//
#include <hip/hip_runtime.h>
#include <hip/hip_bf16.h>
#include <cstdint>

#define NCAMS 6
#define NQ 2500
#define EMBED 256
#define HEADS 8
#define DHEAD 32
#define LTOT 19560
#define MVAL (NCAMS * LTOT) /* 117360 */

typedef __attribute__((ext_vector_type(8))) short bf16x8;
typedef __attribute__((ext_vector_type(4))) float f32x4;

__device__ __forceinline__ unsigned short f2bf(float f) {
  unsigned u = __float_as_uint(f);
  return (unsigned short)((u + 0x7fffu + ((u >> 16) & 1u)) >> 16);
}
__device__ __forceinline__ unsigned short bfbits(float x) {
  __hip_bfloat16 h = __float2bfloat16(x);
  return __builtin_bit_cast(unsigned short, h);
}

// ---------------------------------------------------------------------------
// Kernel P: all weight transposes -> bf16, plus query -> bf16.
// ---------------------------------------------------------------------------
__global__ __launch_bounds__(256) void k_prep(
    const float* __restrict__ Wv, const float* __restrict__ Woff,
    const float* __restrict__ Wattn, const float* __restrict__ Wout,
    const float* __restrict__ query,
    unsigned short* __restrict__ WT, unsigned short* __restrict__ WTq,
    unsigned short* __restrict__ WoutT, unsigned short* __restrict__ qbf)
{
  const int b = blockIdx.x, t = threadIdx.x;
  if (b < 256) {
    WT[(size_t)b * 256 + t] = f2bf(Wv[(size_t)t * 256 + b]);
  } else if (b < 768) {
    int c = b - 256;
    WTq[(size_t)c * 256 + t] = f2bf(Woff[(size_t)t * 512 + c]);
  } else if (b < 1024) {
    int c = b - 768;
    WTq[(size_t)(512 + c) * 256 + t] = f2bf(Wattn[(size_t)t * 256 + c]);
  } else if (b < 1280) {
    int c = b - 1024;
    WoutT[(size_t)c * 256 + t] = f2bf(Wout[(size_t)t * 256 + c]);
  } else {
    int q = b - 1280;
    qbf[(size_t)q * 256 + t] = f2bf(query[(size_t)q * 256 + t]);
  }
}

// ---------------------------------------------------------------------------
// Kernel A (v3): val = bf16( key_feats @ W_value + b_value )
// v1's coalesced staged pipeline (512 thr, 8 waves 2Mx4N, BM=128, BN=256,
// reg ping-pong, 2 barriers/K-step) + SWAPPED MFMA OPERANDS so the C/D
// layout gives each lane 4 consecutive output columns -> direct uint2
// stores, no LDS transpose, no write amplification.
// ---------------------------------------------------------------------------
__global__ __launch_bounds__(512, 6) void k_valproj(
    const float* __restrict__ A,            // (117360, 256) f32
    const unsigned short* __restrict__ WT,  // (256 cols, 256 k) bf16
    const float* __restrict__ bv,           // (256,)
    unsigned short* __restrict__ val)       // (117360, 256) bf16
{
  __shared__ unsigned short As[128 * 64];
  __shared__ unsigned short Bs[256 * 64];
  const int t = threadIdx.x;
  const int lane = t & 63;
  const int wid = t >> 6;
  const int wm = wid >> 2, wn = wid & 3;
  const int laneM = lane & 15, kGrp = lane >> 4;
  const int bm = blockIdx.x * 128;

  const int aG = t & 15, aR0 = t >> 4;  // A: 16 float4-groups/row, 32 rows/pass
  const int bC = t & 7,  bR0 = t >> 3;  // B: 8 16B-chunks/row, 64 rows/pass

  float4 aRegs[2][4];
  uint4  bRegs[2][4];
  f32x4  acc[4][4];
#pragma unroll
  for (int m = 0; m < 4; ++m)
#pragma unroll
    for (int n = 0; n < 4; ++n) acc[m][n] = {0.f, 0.f, 0.f, 0.f};

  // prologue: load K-step 0
#pragma unroll
  for (int p = 0; p < 4; ++p) {
    int row = bm + aR0 + p * 32;
    aRegs[0][p] = (row < MVAL) ? *(const float4*)&A[(size_t)row * 256 + aG * 4]
                               : make_float4(0.f, 0.f, 0.f, 0.f);
    bRegs[0][p] = *(const uint4*)&WT[(size_t)(bR0 + p * 64) * 256 + bC * 8];
  }

#pragma unroll
  for (int kk = 0; kk < 4; ++kk) {
    const int cur = kk & 1, nxt = cur ^ 1;
    if (kk) __syncthreads();
    // ---- store staged regs -> LDS (convert A to bf16), swizzled ----
#pragma unroll
    for (int p = 0; p < 4; ++p) {
      int row = aR0 + p * 32;
      int elem = row * 64 + (((aG >> 1) ^ (row & 7)) << 3) + (aG & 1) * 4;
      float4 a = aRegs[cur][p];
      uint2 u;
      u.x = (unsigned)f2bf(a.x) | ((unsigned)f2bf(a.y) << 16);
      u.y = (unsigned)f2bf(a.z) | ((unsigned)f2bf(a.w) << 16);
      *(uint2*)&As[elem] = u;
    }
#pragma unroll
    for (int p = 0; p < 4; ++p) {
      int row = bR0 + p * 64;
      int elem = row * 64 + ((bC ^ (row & 7)) << 3);
      *(uint4*)&Bs[elem] = bRegs[cur][p];
    }
    __syncthreads();
    // ---- prefetch next K-step ----
    if (kk < 3) {
      const int kn = (kk + 1) * 64;
#pragma unroll
      for (int p = 0; p < 4; ++p) {
        int row = bm + aR0 + p * 32;
        aRegs[nxt][p] = (row < MVAL)
            ? *(const float4*)&A[(size_t)row * 256 + kn + aG * 4]
            : make_float4(0.f, 0.f, 0.f, 0.f);
        bRegs[nxt][p] = *(const uint4*)&WT[(size_t)(bR0 + p * 64) * 256 + kn + bC * 8];
      }
    }
    // ---- MFMA on current LDS tiles (SWAPPED operand order) ----
#pragma unroll
    for (int ks = 0; ks < 2; ++ks) {
      bf16x8 af[4], bfr[4];
#pragma unroll
      for (int m = 0; m < 4; ++m) {
        int row = wm * 64 + m * 16 + laneM;
        af[m] = *(bf16x8*)&As[row * 64 + (((ks * 4 + kGrp) ^ (row & 7)) << 3)];
      }
#pragma unroll
      for (int n = 0; n < 4; ++n) {
        int row = wn * 64 + n * 16 + laneM;
        bfr[n] = *(bf16x8*)&Bs[row * 64 + (((ks * 4 + kGrp) ^ (row & 7)) << 3)];
      }
#pragma unroll
      for (int m = 0; m < 4; ++m)
#pragma unroll
        for (int n = 0; n < 4; ++n)
          acc[m][n] = __builtin_amdgcn_mfma_f32_16x16x32_bf16(bfr[n], af[m], acc[m][n], 0, 0, 0);
    }
  }

  // ---- epilogue: swapped C/D layout -> lane holds row ..+laneM, cols kGrp*4+r
  float4 bb4[4];
#pragma unroll
  for (int n = 0; n < 4; ++n)
    bb4[n] = *(const float4*)&bv[wn * 64 + n * 16 + kGrp * 4];

#pragma unroll
  for (int m = 0; m < 4; ++m) {
    int row = bm + wm * 64 + m * 16 + laneM;
    if (row < MVAL) {
#pragma unroll
      for (int n = 0; n < 4; ++n) {
        uint2 u;
        u.x = (unsigned)bfbits(acc[m][n][0] + bb4[n].x) |
              ((unsigned)bfbits(acc[m][n][1] + bb4[n].y) << 16);
        u.y = (unsigned)bfbits(acc[m][n][2] + bb4[n].z) |
              ((unsigned)bfbits(acc[m][n][3] + bb4[n].w) << 16);
        *(uint2*)&val[(size_t)row * 256 + wn * 64 + n * 16 + kGrp * 4] = u;
      }
    }
  }
}

// ---------------------------------------------------------------------------
// Kernel G: generic small-M GEMM.  C(M,N) = A_bf16(M,256) @ BT_bf16(N,256)^T
//           + bias (split ba/bb at bsplit) [+ resid(M,256) if withResid]
// ---------------------------------------------------------------------------
__global__ __launch_bounds__(256, 2) void k_gemm_small(
    const unsigned short* __restrict__ A,
    const unsigned short* __restrict__ BT,
    const float* __restrict__ ba, const float* __restrict__ bb, int bsplit,
    const float* __restrict__ resid,
    float* __restrict__ C, int M, int N, int withResid)
{
  __shared__ unsigned short As[128 * 64];
  __shared__ unsigned short Bs[128 * 64];
  const int t = threadIdx.x;
  const int lane = t & 63;
  const int wid = t >> 6;
  const int wm = wid >> 1, wn = wid & 1;
  const int laneM = lane & 15, kGrp = lane >> 4;
  const int bm = blockIdx.x * 128;
  const int bn = blockIdx.y * 128;

  const int aC = t & 7, aR0 = t >> 3;

  uint4 aRegs[2][4];
  uint4 bRegs[2][4];
  f32x4 acc[4][4];
#pragma unroll
  for (int m = 0; m < 4; ++m)
#pragma unroll
    for (int n = 0; n < 4; ++n) acc[m][n] = {0.f, 0.f, 0.f, 0.f};

#pragma unroll
  for (int p = 0; p < 4; ++p) {
    int arow = bm + aR0 + p * 32;
    aRegs[0][p] = (arow < M) ? *(const uint4*)&A[(size_t)arow * 256 + aC * 8]
                             : make_uint4(0u, 0u, 0u, 0u);
    bRegs[0][p] = *(const uint4*)&BT[(size_t)(bn + aR0 + p * 32) * 256 + aC * 8];
  }

#pragma unroll
  for (int kk = 0; kk < 4; ++kk) {
    const int cur = kk & 1, nxt = cur ^ 1;
    if (kk) __syncthreads();
#pragma unroll
    for (int p = 0; p < 4; ++p) {
      int row = aR0 + p * 32;
      int elem = row * 64 + ((aC ^ (row & 7)) << 3);
      *(uint4*)&As[elem] = aRegs[cur][p];
      *(uint4*)&Bs[elem] = bRegs[cur][p];
    }
    __syncthreads();
    if (kk < 3) {
      const int kn = (kk + 1) * 64;
#pragma unroll
      for (int p = 0; p < 4; ++p) {
        int arow = bm + aR0 + p * 32;
        aRegs[nxt][p] = (arow < M)
            ? *(const uint4*)&A[(size_t)arow * 256 + kn + aC * 8]
            : make_uint4(0u, 0u, 0u, 0u);
        bRegs[nxt][p] = *(const uint4*)&BT[(size_t)(bn + aR0 + p * 32) * 256 + kn + aC * 8];
      }
    }
#pragma unroll
    for (int ks = 0; ks < 2; ++ks) {
      bf16x8 af[4], bfr[4];
#pragma unroll
      for (int m = 0; m < 4; ++m) {
        int row = wm * 64 + m * 16 + laneM;
        af[m] = *(bf16x8*)&As[row * 64 + (((ks * 4 + kGrp) ^ (row & 7)) << 3)];
      }
#pragma unroll
      for (int n = 0; n < 4; ++n) {
        int row = wn * 64 + n * 16 + laneM;
        bfr[n] = *(bf16x8*)&Bs[row * 64 + (((ks * 4 + kGrp) ^ (row & 7)) << 3)];
      }
#pragma unroll
      for (int m = 0; m < 4; ++m)
#pragma unroll
        for (int n = 0; n < 4; ++n)
          acc[m][n] = __builtin_amdgcn_mfma_f32_16x16x32_bf16(af[m], bfr[n], acc[m][n], 0, 0, 0);
    }
  }

  float bvn[4];
#pragma unroll
  for (int n = 0; n < 4; ++n) {
    int col = bn + wn * 64 + n * 16 + laneM;
    bvn[n] = (col < bsplit) ? ba[col] : bb[col - bsplit];
  }
#pragma unroll
  for (int m = 0; m < 4; ++m) {
#pragma unroll
    for (int r = 0; r < 4; ++r) {
      int row = bm + wm * 64 + m * 16 + kGrp * 4 + r;
      if (row < M) {
#pragma unroll
        for (int n = 0; n < 4; ++n) {
          int col = bn + wn * 64 + n * 16 + laneM;
          float v = acc[m][n][r] + bvn[n];
          if (withResid) v += resid[(size_t)row * 256 + col];
          C[(size_t)row * N + col] = v;
        }
      }
    }
  }
}

// ---------------------------------------------------------------------------
// Kernel M: bev_mask -> valid[6*2500], on-device dtype detect (int32 vs u8).
// ---------------------------------------------------------------------------
__global__ __launch_bounds__(256) void k_maskvalid(
    const unsigned char* __restrict__ MSK,
    unsigned char* __restrict__ valid)
{
  __shared__ int s_u8;
  const int t = threadIdx.x;
  if (t == 0) s_u8 = 0;
  __syncthreads();
  if ((t & 3) && MSK[t]) atomicOr(&s_u8, 1);
  __syncthreads();
  const int isU8 = s_u8;

  const int i = blockIdx.x * 256 + t;
  if (i < NCAMS * NQ) {
    int any;
    if (isU8) {
      const unsigned char* p = MSK + (size_t)i * 4;
      any = p[0] | p[1] | p[2] | p[3];
    } else {
      const int* p = (const int*)MSK + (size_t)i * 4;
      any = p[0] | p[1] | p[2] | p[3];
    }
    valid[i] = any ? 1 : 0;
  }
}

// ---------------------------------------------------------------------------
// Kernel C (two-phase sampling).  OFFLOG row = [OFF(512) | LOG(256)].
// ---------------------------------------------------------------------------
__global__ __launch_bounds__(256) void k_sample(
    const unsigned short* __restrict__ val,   // (117360, 256) bf16
    const float* __restrict__ OFFLOG,         // (2500, 768)
    const float* __restrict__ REF,            // (6,1,2500,4,2)
    const unsigned char* __restrict__ valid,  // (6,2500)
    unsigned short* __restrict__ slots)       // (2500,256) bf16
{
  __shared__ int2  s_pack[4][NCAMS][256];
  __shared__ float s_off[512];
  __shared__ float s_ref[48];
  __shared__ int   s_valid[6];

  const int q = blockIdx.x;
  const int t = threadIdx.x;

  s_off[t]       = OFFLOG[(size_t)q * 768 + t];
  s_off[t + 256] = OFFLOG[(size_t)q * 768 + 256 + t];
  if (t < 48) s_ref[t] = REF[(size_t)(t >> 3) * (NQ * 8) + (size_t)q * 8 + (t & 7)];
  if (t < 6) s_valid[t] = valid[(size_t)t * NQ + q];

  float logit = OFFLOG[(size_t)q * 768 + 512 + t];
  float m = logit;
#pragma unroll
  for (int o = 16; o > 0; o >>= 1) m = fmaxf(m, __shfl_xor(m, o, 32));
  float e = __expf(logit - m);
  float s = e;
#pragma unroll
  for (int o = 16; o > 0; o >>= 1) s += __shfl_xor(s, o, 32);
  const float a = e / s;
  __syncthreads();

  {
    const int h1 = t >> 5, lp = t & 31, lvl = lp >> 3, p = lp & 7, z = p & 3;
    const int WW = 160 >> lvl;
    const int HH = (lvl < 3) ? (92 >> lvl) : 12;
    const int S  = (lvl == 0) ? 0 : (lvl == 1) ? 14720 : (lvl == 2) ? 18400 : 19320;
    const float Wf = (float)WW, Hf = (float)HH;
    const float ox = s_off[h1 * 64 + lp * 2];
    const float oy = s_off[h1 * 64 + lp * 2 + 1];
#pragma unroll 1
    for (int cam = 0; cam < NCAMS; ++cam) {
      if (!s_valid[cam]) continue;
      float rx = s_ref[cam * 8 + z * 2];
      float ry = s_ref[cam * 8 + z * 2 + 1];
      float x = rx * Wf + ox - 0.5f;
      float y = ry * Hf + oy - 0.5f;
      float x0f = floorf(x), y0f = floorf(y);
      float fx = x - x0f, fy = y - y0f;
      int x0 = (int)x0f, y0 = (int)y0f;
      int base = cam * LTOT + S;
#pragma unroll
      for (int dy = 0; dy < 2; ++dy) {
        int yi = y0 + dy;
        float wy = dy ? fy : 1.f - fy;
        int yc = min(max(yi, 0), HH - 1);
        bool vy = (yi >= 0) && (yi < HH);
#pragma unroll
        for (int dx = 0; dx < 2; ++dx) {
          int xi = x0 + dx;
          float wx = dx ? fx : 1.f - fx;
          int xc = min(max(xi, 0), WW - 1);
          bool vv = vy && (xi >= 0) && (xi < WW);
          float wgt = vv ? wx * wy * a : 0.f;
          int addr = (base + yc * WW + xc) * 512;
          s_pack[dy * 2 + dx][cam][t] = make_int2(addr, __float_as_int(wgt));
        }
      }
    }
  }
  __syncthreads();

  const int h = t >> 5, pp = (t >> 3) & 3, l8 = t & 7;
  const unsigned dconst = (unsigned)(h * 64 + l8 * 8);
  const char* vb = (const char*)val;
  int nvalid = s_valid[0] + s_valid[1] + s_valid[2] + s_valid[3] + s_valid[4] + s_valid[5];
  float inv = 1.f / fmaxf((float)nvalid, 1.f);

  f32x4 acc = {0.f, 0.f, 0.f, 0.f};
#pragma unroll 1
  for (int cam = 0; cam < NCAMS; ++cam) {
    if (!s_valid[cam]) continue;
#pragma unroll
    for (int it = 0; it < 8; ++it) {
      const int idx = h * 32 + pp + it * 4;
      int2 pk0 = s_pack[0][cam][idx];
      int2 pk1 = s_pack[1][cam][idx];
      int2 pk2 = s_pack[2][cam][idx];
      int2 pk3 = s_pack[3][cam][idx];
      uint2 v0 = *(const uint2*)(vb + (size_t)((unsigned)pk0.x + dconst));
      uint2 v1 = *(const uint2*)(vb + (size_t)((unsigned)pk1.x + dconst));
      uint2 v2 = *(const uint2*)(vb + (size_t)((unsigned)pk2.x + dconst));
      uint2 v3 = *(const uint2*)(vb + (size_t)((unsigned)pk3.x + dconst));
      float w0 = __int_as_float(pk0.y), w1 = __int_as_float(pk1.y);
      float w2 = __int_as_float(pk2.y), w3 = __int_as_float(pk3.y);
      acc[0] += w0 * __uint_as_float(v0.x << 16);
      acc[1] += w0 * __uint_as_float(v0.x & 0xffff0000u);
      acc[2] += w0 * __uint_as_float(v0.y << 16);
      acc[3] += w0 * __uint_as_float(v0.y & 0xffff0000u);
      acc[0] += w1 * __uint_as_float(v1.x << 16);
      acc[1] += w1 * __uint_as_float(v1.x & 0xffff0000u);
      acc[2] += w1 * __uint_as_float(v1.y << 16);
      acc[3] += w1 * __uint_as_float(v1.y & 0xffff0000u);
      acc[0] += w2 * __uint_as_float(v2.x << 16);
      acc[1] += w2 * __uint_as_float(v2.x & 0xffff0000u);
      acc[2] += w2 * __uint_as_float(v2.y << 16);
      acc[3] += w2 * __uint_as_float(v2.y & 0xffff0000u);
      acc[0] += w3 * __uint_as_float(v3.x << 16);
      acc[1] += w3 * __uint_as_float(v3.x & 0xffff0000u);
      acc[2] += w3 * __uint_as_float(v3.y << 16);
      acc[3] += w3 * __uint_as_float(v3.y & 0xffff0000u);
    }
  }

#pragma unroll
  for (int i = 0; i < 4; ++i) {
    acc[i] += __shfl_xor(acc[i], 8);
    acc[i] += __shfl_xor(acc[i], 16);
  }
  if (pp == 0) {
    uint2 r;
    r.x = (unsigned)f2bf(acc[0] * inv) | ((unsigned)f2bf(acc[1] * inv) << 16);
    r.y = (unsigned)f2bf(acc[2] * inv) | ((unsigned)f2bf(acc[3] * inv) << 16);
    *(uint2*)&slots[(size_t)q * 256 + h * 32 + l8 * 4] = r;
  }
}

// ---------------------------------------------------------------------------
extern "C" void kernel_launch(void* const* d_in, const int* in_sizes, int n_in,
                              void* d_out, int out_size, void* d_ws, size_t ws_size,
                              hipStream_t stream) {
  const float* query     = (const float*)d_in[0];
  const float* key_feats = (const float*)d_in[1];
  const float* ref       = (const float*)d_in[2];
  const unsigned char* mask = (const unsigned char*)d_in[3];
  // d_in[4] = spatial_shapes (compile-time constants)
  const float* Wv    = (const float*)d_in[5];
  const float* bv    = (const float*)d_in[6];
  const float* Woff  = (const float*)d_in[7];
  const float* boff  = (const float*)d_in[8];
  const float* Wattn = (const float*)d_in[9];
  const float* battn = (const float*)d_in[10];
  const float* Wout  = (const float*)d_in[11];
  const float* bout  = (const float*)d_in[12];
  float* out = (float*)d_out;

  char* ws = (char*)d_ws;
  size_t off = 0;
  unsigned short* val   = (unsigned short*)(ws + off); off += (size_t)MVAL * 256 * 2;
  unsigned short* WT    = (unsigned short*)(ws + off); off += 256 * 256 * 2;
  unsigned short* WTq   = (unsigned short*)(ws + off); off += 768 * 256 * 2;
  unsigned short* WoutT = (unsigned short*)(ws + off); off += 256 * 256 * 2;
  unsigned short* qbf   = (unsigned short*)(ws + off); off += (size_t)NQ * 256 * 2;
  float* OFFLOG = (float*)(ws + off); off += (size_t)NQ * 768 * 4;
  unsigned short* slots = (unsigned short*)(ws + off); off += (size_t)NQ * 256 * 2;
  unsigned char* valid  = (unsigned char*)(ws + off); off += NCAMS * NQ;

  hipLaunchKernelGGL(k_prep, dim3(1280 + NQ), dim3(256), 0, stream,
                     Wv, Woff, Wattn, Wout, query, WT, WTq, WoutT, qbf);
  hipLaunchKernelGGL(k_valproj, dim3((MVAL + 127) / 128), dim3(512), 0, stream,
                     key_feats, WT, bv, val);
  hipLaunchKernelGGL(k_gemm_small, dim3((NQ + 127) / 128, 6), dim3(256), 0, stream,
                     qbf, WTq, boff, battn, 512, (const float*)nullptr, OFFLOG, NQ, 768, 0);
  hipLaunchKernelGGL(k_maskvalid, dim3((NCAMS * NQ + 255) / 256), dim3(256), 0, stream,
                     mask, valid);
  hipLaunchKernelGGL(k_sample, dim3(NQ), dim3(256), 0, stream,
                     val, OFFLOG, ref, valid, slots);
  hipLaunchKernelGGL(k_gemm_small, dim3((NQ + 127) / 128, 2), dim3(256), 0, stream,
                     slots, WoutT, bout, bout, 1 << 30, query, out, NQ, 256, 1);
}

// Round 8
// 193.883 us; speedup vs baseline: 2.1299x; 2.1299x over previous
//
#include <hip/hip_runtime.h>
#include <hip/hip_bf16.h>
#include <cstdint>

#define NCAMS 6
#define NQ 2500
#define EMBED 256
#define HEADS 8
#define DHEAD 32
#define LTOT 19560
#define MVAL (NCAMS * LTOT) /* 117360 */

typedef __attribute__((ext_vector_type(8))) short bf16x8;
typedef __attribute__((ext_vector_type(4))) float f32x4;

__device__ __forceinline__ unsigned short f2bf(float f) {
  unsigned u = __float_as_uint(f);
  return (unsigned short)((u + 0x7fffu + ((u >> 16) & 1u)) >> 16);
}
__device__ __forceinline__ unsigned short bfbits(float x) {
  __hip_bfloat16 h = __float2bfloat16(x);
  return __builtin_bit_cast(unsigned short, h);
}

// ---------------------------------------------------------------------------
// Kernel P: all weight transposes -> bf16, plus query -> bf16.
// ---------------------------------------------------------------------------
__global__ __launch_bounds__(256) void k_prep(
    const float* __restrict__ Wv, const float* __restrict__ Woff,
    const float* __restrict__ Wattn, const float* __restrict__ Wout,
    const float* __restrict__ query,
    unsigned short* __restrict__ WT, unsigned short* __restrict__ WTq,
    unsigned short* __restrict__ WoutT, unsigned short* __restrict__ qbf)
{
  const int b = blockIdx.x, t = threadIdx.x;
  if (b < 256) {
    WT[(size_t)b * 256 + t] = f2bf(Wv[(size_t)t * 256 + b]);
  } else if (b < 768) {
    int c = b - 256;
    WTq[(size_t)c * 256 + t] = f2bf(Woff[(size_t)t * 512 + c]);
  } else if (b < 1024) {
    int c = b - 768;
    WTq[(size_t)(512 + c) * 256 + t] = f2bf(Wattn[(size_t)t * 256 + c]);
  } else if (b < 1280) {
    int c = b - 1024;
    WoutT[(size_t)c * 256 + t] = f2bf(Wout[(size_t)t * 256 + c]);
  } else {
    int q = b - 1280;
    qbf[(size_t)q * 256 + t] = f2bf(query[(size_t)q * 256 + t]);
  }
}

// ---------------------------------------------------------------------------
// Kernel A (v4): val = bf16( key_feats @ W_value + b_value )
// Round-5 staged pipeline (512 thr, 8 waves 2Mx4N, BM=128, BN=256, reg
// ping-pong, launch_bounds(512,2): VGPR 84, no spill) + swapped MFMA
// operands so each lane stores 4 consecutive columns (uint2) -> WRITE_SIZE
// 170MB -> 59MB.  NOTE: launch_bounds 2nd arg >2 caused a 40-VGPR cap and
// catastrophic scratch spill (round 7) -- keep at 2.
// ---------------------------------------------------------------------------
__global__ __launch_bounds__(512, 2) void k_valproj(
    const float* __restrict__ A,            // (117360, 256) f32
    const unsigned short* __restrict__ WT,  // (256 cols, 256 k) bf16
    const float* __restrict__ bv,           // (256,)
    unsigned short* __restrict__ val)       // (117360, 256) bf16
{
  __shared__ unsigned short As[128 * 64];
  __shared__ unsigned short Bs[256 * 64];
  const int t = threadIdx.x;
  const int lane = t & 63;
  const int wid = t >> 6;
  const int wm = wid >> 2, wn = wid & 3;
  const int laneM = lane & 15, kGrp = lane >> 4;
  const int bm = blockIdx.x * 128;

  const int aG = t & 15, aR0 = t >> 4;  // A: 16 float4-groups/row, 32 rows/pass
  const int bC = t & 7,  bR0 = t >> 3;  // B: 8 16B-chunks/row, 64 rows/pass

  float4 aRegs[2][4];
  uint4  bRegs[2][4];
  f32x4  acc[4][4];
#pragma unroll
  for (int m = 0; m < 4; ++m)
#pragma unroll
    for (int n = 0; n < 4; ++n) acc[m][n] = {0.f, 0.f, 0.f, 0.f};

  // prologue: load K-step 0
#pragma unroll
  for (int p = 0; p < 4; ++p) {
    int row = bm + aR0 + p * 32;
    aRegs[0][p] = (row < MVAL) ? *(const float4*)&A[(size_t)row * 256 + aG * 4]
                               : make_float4(0.f, 0.f, 0.f, 0.f);
    bRegs[0][p] = *(const uint4*)&WT[(size_t)(bR0 + p * 64) * 256 + bC * 8];
  }

#pragma unroll
  for (int kk = 0; kk < 4; ++kk) {
    const int cur = kk & 1, nxt = cur ^ 1;
    if (kk) __syncthreads();
    // ---- store staged regs -> LDS (convert A to bf16), swizzled ----
#pragma unroll
    for (int p = 0; p < 4; ++p) {
      int row = aR0 + p * 32;
      int elem = row * 64 + (((aG >> 1) ^ (row & 7)) << 3) + (aG & 1) * 4;
      float4 a = aRegs[cur][p];
      uint2 u;
      u.x = (unsigned)f2bf(a.x) | ((unsigned)f2bf(a.y) << 16);
      u.y = (unsigned)f2bf(a.z) | ((unsigned)f2bf(a.w) << 16);
      *(uint2*)&As[elem] = u;
    }
#pragma unroll
    for (int p = 0; p < 4; ++p) {
      int row = bR0 + p * 64;
      int elem = row * 64 + ((bC ^ (row & 7)) << 3);
      *(uint4*)&Bs[elem] = bRegs[cur][p];
    }
    __syncthreads();
    // ---- prefetch next K-step ----
    if (kk < 3) {
      const int kn = (kk + 1) * 64;
#pragma unroll
      for (int p = 0; p < 4; ++p) {
        int row = bm + aR0 + p * 32;
        aRegs[nxt][p] = (row < MVAL)
            ? *(const float4*)&A[(size_t)row * 256 + kn + aG * 4]
            : make_float4(0.f, 0.f, 0.f, 0.f);
        bRegs[nxt][p] = *(const uint4*)&WT[(size_t)(bR0 + p * 64) * 256 + kn + bC * 8];
      }
    }
    // ---- MFMA on current LDS tiles (SWAPPED operand order) ----
#pragma unroll
    for (int ks = 0; ks < 2; ++ks) {
      bf16x8 af[4], bfr[4];
#pragma unroll
      for (int m = 0; m < 4; ++m) {
        int row = wm * 64 + m * 16 + laneM;
        af[m] = *(bf16x8*)&As[row * 64 + (((ks * 4 + kGrp) ^ (row & 7)) << 3)];
      }
#pragma unroll
      for (int n = 0; n < 4; ++n) {
        int row = wn * 64 + n * 16 + laneM;
        bfr[n] = *(bf16x8*)&Bs[row * 64 + (((ks * 4 + kGrp) ^ (row & 7)) << 3)];
      }
#pragma unroll
      for (int m = 0; m < 4; ++m)
#pragma unroll
        for (int n = 0; n < 4; ++n)
          acc[m][n] = __builtin_amdgcn_mfma_f32_16x16x32_bf16(bfr[n], af[m], acc[m][n], 0, 0, 0);
    }
  }

  // ---- epilogue: swapped C/D layout -> lane holds row ..+laneM, cols kGrp*4+r
  float4 bb4[4];
#pragma unroll
  for (int n = 0; n < 4; ++n)
    bb4[n] = *(const float4*)&bv[wn * 64 + n * 16 + kGrp * 4];

#pragma unroll
  for (int m = 0; m < 4; ++m) {
    int row = bm + wm * 64 + m * 16 + laneM;
    if (row < MVAL) {
#pragma unroll
      for (int n = 0; n < 4; ++n) {
        uint2 u;
        u.x = (unsigned)bfbits(acc[m][n][0] + bb4[n].x) |
              ((unsigned)bfbits(acc[m][n][1] + bb4[n].y) << 16);
        u.y = (unsigned)bfbits(acc[m][n][2] + bb4[n].z) |
              ((unsigned)bfbits(acc[m][n][3] + bb4[n].w) << 16);
        *(uint2*)&val[(size_t)row * 256 + wn * 64 + n * 16 + kGrp * 4] = u;
      }
    }
  }
}

// ---------------------------------------------------------------------------
// Kernel G: generic small-M GEMM.  C(M,N) = A_bf16(M,256) @ BT_bf16(N,256)^T
//           + bias (split ba/bb at bsplit) [+ resid(M,256) if withResid]
// ---------------------------------------------------------------------------
__global__ __launch_bounds__(256, 2) void k_gemm_small(
    const unsigned short* __restrict__ A,
    const unsigned short* __restrict__ BT,
    const float* __restrict__ ba, const float* __restrict__ bb, int bsplit,
    const float* __restrict__ resid,
    float* __restrict__ C, int M, int N, int withResid)
{
  __shared__ unsigned short As[128 * 64];
  __shared__ unsigned short Bs[128 * 64];
  const int t = threadIdx.x;
  const int lane = t & 63;
  const int wid = t >> 6;
  const int wm = wid >> 1, wn = wid & 1;
  const int laneM = lane & 15, kGrp = lane >> 4;
  const int bm = blockIdx.x * 128;
  const int bn = blockIdx.y * 128;

  const int aC = t & 7, aR0 = t >> 3;

  uint4 aRegs[2][4];
  uint4 bRegs[2][4];
  f32x4 acc[4][4];
#pragma unroll
  for (int m = 0; m < 4; ++m)
#pragma unroll
    for (int n = 0; n < 4; ++n) acc[m][n] = {0.f, 0.f, 0.f, 0.f};

#pragma unroll
  for (int p = 0; p < 4; ++p) {
    int arow = bm + aR0 + p * 32;
    aRegs[0][p] = (arow < M) ? *(const uint4*)&A[(size_t)arow * 256 + aC * 8]
                             : make_uint4(0u, 0u, 0u, 0u);
    bRegs[0][p] = *(const uint4*)&BT[(size_t)(bn + aR0 + p * 32) * 256 + aC * 8];
  }

#pragma unroll
  for (int kk = 0; kk < 4; ++kk) {
    const int cur = kk & 1, nxt = cur ^ 1;
    if (kk) __syncthreads();
#pragma unroll
    for (int p = 0; p < 4; ++p) {
      int row = aR0 + p * 32;
      int elem = row * 64 + ((aC ^ (row & 7)) << 3);
      *(uint4*)&As[elem] = aRegs[cur][p];
      *(uint4*)&Bs[elem] = bRegs[cur][p];
    }
    __syncthreads();
    if (kk < 3) {
      const int kn = (kk + 1) * 64;
#pragma unroll
      for (int p = 0; p < 4; ++p) {
        int arow = bm + aR0 + p * 32;
        aRegs[nxt][p] = (arow < M)
            ? *(const uint4*)&A[(size_t)arow * 256 + kn + aC * 8]
            : make_uint4(0u, 0u, 0u, 0u);
        bRegs[nxt][p] = *(const uint4*)&BT[(size_t)(bn + aR0 + p * 32) * 256 + kn + aC * 8];
      }
    }
#pragma unroll
    for (int ks = 0; ks < 2; ++ks) {
      bf16x8 af[4], bfr[4];
#pragma unroll
      for (int m = 0; m < 4; ++m) {
        int row = wm * 64 + m * 16 + laneM;
        af[m] = *(bf16x8*)&As[row * 64 + (((ks * 4 + kGrp) ^ (row & 7)) << 3)];
      }
#pragma unroll
      for (int n = 0; n < 4; ++n) {
        int row = wn * 64 + n * 16 + laneM;
        bfr[n] = *(bf16x8*)&Bs[row * 64 + (((ks * 4 + kGrp) ^ (row & 7)) << 3)];
      }
#pragma unroll
      for (int m = 0; m < 4; ++m)
#pragma unroll
        for (int n = 0; n < 4; ++n)
          acc[m][n] = __builtin_amdgcn_mfma_f32_16x16x32_bf16(af[m], bfr[n], acc[m][n], 0, 0, 0);
    }
  }

  float bvn[4];
#pragma unroll
  for (int n = 0; n < 4; ++n) {
    int col = bn + wn * 64 + n * 16 + laneM;
    bvn[n] = (col < bsplit) ? ba[col] : bb[col - bsplit];
  }
#pragma unroll
  for (int m = 0; m < 4; ++m) {
#pragma unroll
    for (int r = 0; r < 4; ++r) {
      int row = bm + wm * 64 + m * 16 + kGrp * 4 + r;
      if (row < M) {
#pragma unroll
        for (int n = 0; n < 4; ++n) {
          int col = bn + wn * 64 + n * 16 + laneM;
          float v = acc[m][n][r] + bvn[n];
          if (withResid) v += resid[(size_t)row * 256 + col];
          C[(size_t)row * N + col] = v;
        }
      }
    }
  }
}

// ---------------------------------------------------------------------------
// Kernel M: bev_mask -> valid[6*2500], on-device dtype detect (int32 vs u8).
// ---------------------------------------------------------------------------
__global__ __launch_bounds__(256) void k_maskvalid(
    const unsigned char* __restrict__ MSK,
    unsigned char* __restrict__ valid)
{
  __shared__ int s_u8;
  const int t = threadIdx.x;
  if (t == 0) s_u8 = 0;
  __syncthreads();
  if ((t & 3) && MSK[t]) atomicOr(&s_u8, 1);
  __syncthreads();
  const int isU8 = s_u8;

  const int i = blockIdx.x * 256 + t;
  if (i < NCAMS * NQ) {
    int any;
    if (isU8) {
      const unsigned char* p = MSK + (size_t)i * 4;
      any = p[0] | p[1] | p[2] | p[3];
    } else {
      const int* p = (const int*)MSK + (size_t)i * 4;
      any = p[0] | p[1] | p[2] | p[3];
    }
    valid[i] = any ? 1 : 0;
  }
}

// ---------------------------------------------------------------------------
// Kernel C (two-phase sampling).  OFFLOG row = [OFF(512) | LOG(256)].
// ---------------------------------------------------------------------------
__global__ __launch_bounds__(256) void k_sample(
    const unsigned short* __restrict__ val,   // (117360, 256) bf16
    const float* __restrict__ OFFLOG,         // (2500, 768)
    const float* __restrict__ REF,            // (6,1,2500,4,2)
    const unsigned char* __restrict__ valid,  // (6,2500)
    unsigned short* __restrict__ slots)       // (2500,256) bf16
{
  __shared__ int2  s_pack[4][NCAMS][256];
  __shared__ float s_off[512];
  __shared__ float s_ref[48];
  __shared__ int   s_valid[6];

  const int q = blockIdx.x;
  const int t = threadIdx.x;

  s_off[t]       = OFFLOG[(size_t)q * 768 + t];
  s_off[t + 256] = OFFLOG[(size_t)q * 768 + 256 + t];
  if (t < 48) s_ref[t] = REF[(size_t)(t >> 3) * (NQ * 8) + (size_t)q * 8 + (t & 7)];
  if (t < 6) s_valid[t] = valid[(size_t)t * NQ + q];

  float logit = OFFLOG[(size_t)q * 768 + 512 + t];
  float m = logit;
#pragma unroll
  for (int o = 16; o > 0; o >>= 1) m = fmaxf(m, __shfl_xor(m, o, 32));
  float e = __expf(logit - m);
  float s = e;
#pragma unroll
  for (int o = 16; o > 0; o >>= 1) s += __shfl_xor(s, o, 32);
  const float a = e / s;
  __syncthreads();

  {
    const int h1 = t >> 5, lp = t & 31, lvl = lp >> 3, p = lp & 7, z = p & 3;
    const int WW = 160 >> lvl;
    const int HH = (lvl < 3) ? (92 >> lvl) : 12;
    const int S  = (lvl == 0) ? 0 : (lvl == 1) ? 14720 : (lvl == 2) ? 18400 : 19320;
    const float Wf = (float)WW, Hf = (float)HH;
    const float ox = s_off[h1 * 64 + lp * 2];
    const float oy = s_off[h1 * 64 + lp * 2 + 1];
#pragma unroll 1
    for (int cam = 0; cam < NCAMS; ++cam) {
      if (!s_valid[cam]) continue;
      float rx = s_ref[cam * 8 + z * 2];
      float ry = s_ref[cam * 8 + z * 2 + 1];
      float x = rx * Wf + ox - 0.5f;
      float y = ry * Hf + oy - 0.5f;
      float x0f = floorf(x), y0f = floorf(y);
      float fx = x - x0f, fy = y - y0f;
      int x0 = (int)x0f, y0 = (int)y0f;
      int base = cam * LTOT + S;
#pragma unroll
      for (int dy = 0; dy < 2; ++dy) {
        int yi = y0 + dy;
        float wy = dy ? fy : 1.f - fy;
        int yc = min(max(yi, 0), HH - 1);
        bool vy = (yi >= 0) && (yi < HH);
#pragma unroll
        for (int dx = 0; dx < 2; ++dx) {
          int xi = x0 + dx;
          float wx = dx ? fx : 1.f - fx;
          int xc = min(max(xi, 0), WW - 1);
          bool vv = vy && (xi >= 0) && (xi < WW);
          float wgt = vv ? wx * wy * a : 0.f;
          int addr = (base + yc * WW + xc) * 512;
          s_pack[dy * 2 + dx][cam][t] = make_int2(addr, __float_as_int(wgt));
        }
      }
    }
  }
  __syncthreads();

  const int h = t >> 5, pp = (t >> 3) & 3, l8 = t & 7;
  const unsigned dconst = (unsigned)(h * 64 + l8 * 8);
  const char* vb = (const char*)val;
  int nvalid = s_valid[0] + s_valid[1] + s_valid[2] + s_valid[3] + s_valid[4] + s_valid[5];
  float inv = 1.f / fmaxf((float)nvalid, 1.f);

  f32x4 acc = {0.f, 0.f, 0.f, 0.f};
#pragma unroll 1
  for (int cam = 0; cam < NCAMS; ++cam) {
    if (!s_valid[cam]) continue;
#pragma unroll
    for (int it = 0; it < 8; ++it) {
      const int idx = h * 32 + pp + it * 4;
      int2 pk0 = s_pack[0][cam][idx];
      int2 pk1 = s_pack[1][cam][idx];
      int2 pk2 = s_pack[2][cam][idx];
      int2 pk3 = s_pack[3][cam][idx];
      uint2 v0 = *(const uint2*)(vb + (size_t)((unsigned)pk0.x + dconst));
      uint2 v1 = *(const uint2*)(vb + (size_t)((unsigned)pk1.x + dconst));
      uint2 v2 = *(const uint2*)(vb + (size_t)((unsigned)pk2.x + dconst));
      uint2 v3 = *(const uint2*)(vb + (size_t)((unsigned)pk3.x + dconst));
      float w0 = __int_as_float(pk0.y), w1 = __int_as_float(pk1.y);
      float w2 = __int_as_float(pk2.y), w3 = __int_as_float(pk3.y);
      acc[0] += w0 * __uint_as_float(v0.x << 16);
      acc[1] += w0 * __uint_as_float(v0.x & 0xffff0000u);
      acc[2] += w0 * __uint_as_float(v0.y << 16);
      acc[3] += w0 * __uint_as_float(v0.y & 0xffff0000u);
      acc[0] += w1 * __uint_as_float(v1.x << 16);
      acc[1] += w1 * __uint_as_float(v1.x & 0xffff0000u);
      acc[2] += w1 * __uint_as_float(v1.y << 16);
      acc[3] += w1 * __uint_as_float(v1.y & 0xffff0000u);
      acc[0] += w2 * __uint_as_float(v2.x << 16);
      acc[1] += w2 * __uint_as_float(v2.x & 0xffff0000u);
      acc[2] += w2 * __uint_as_float(v2.y << 16);
      acc[3] += w2 * __uint_as_float(v2.y & 0xffff0000u);
      acc[0] += w3 * __uint_as_float(v3.x << 16);
      acc[1] += w3 * __uint_as_float(v3.x & 0xffff0000u);
      acc[2] += w3 * __uint_as_float(v3.y << 16);
      acc[3] += w3 * __uint_as_float(v3.y & 0xffff0000u);
    }
  }

#pragma unroll
  for (int i = 0; i < 4; ++i) {
    acc[i] += __shfl_xor(acc[i], 8);
    acc[i] += __shfl_xor(acc[i], 16);
  }
  if (pp == 0) {
    uint2 r;
    r.x = (unsigned)f2bf(acc[0] * inv) | ((unsigned)f2bf(acc[1] * inv) << 16);
    r.y = (unsigned)f2bf(acc[2] * inv) | ((unsigned)f2bf(acc[3] * inv) << 16);
    *(uint2*)&slots[(size_t)q * 256 + h * 32 + l8 * 4] = r;
  }
}

// ---------------------------------------------------------------------------
extern "C" void kernel_launch(void* const* d_in, const int* in_sizes, int n_in,
                              void* d_out, int out_size, void* d_ws, size_t ws_size,
                              hipStream_t stream) {
  const float* query     = (const float*)d_in[0];
  const float* key_feats = (const float*)d_in[1];
  const float* ref       = (const float*)d_in[2];
  const unsigned char* mask = (const unsigned char*)d_in[3];
  // d_in[4] = spatial_shapes (compile-time constants)
  const float* Wv    = (const float*)d_in[5];
  const float* bv    = (const float*)d_in[6];
  const float* Woff  = (const float*)d_in[7];
  const float* boff  = (const float*)d_in[8];
  const float* Wattn = (const float*)d_in[9];
  const float* battn = (const float*)d_in[10];
  const float* Wout  = (const float*)d_in[11];
  const float* bout  = (const float*)d_in[12];
  float* out = (float*)d_out;

  char* ws = (char*)d_ws;
  size_t off = 0;
  unsigned short* val   = (unsigned short*)(ws + off); off += (size_t)MVAL * 256 * 2;
  unsigned short* WT    = (unsigned short*)(ws + off); off += 256 * 256 * 2;
  unsigned short* WTq   = (unsigned short*)(ws + off); off += 768 * 256 * 2;
  unsigned short* WoutT = (unsigned short*)(ws + off); off += 256 * 256 * 2;
  unsigned short* qbf   = (unsigned short*)(ws + off); off += (size_t)NQ * 256 * 2;
  float* OFFLOG = (float*)(ws + off); off += (size_t)NQ * 768 * 4;
  unsigned short* slots = (unsigned short*)(ws + off); off += (size_t)NQ * 256 * 2;
  unsigned char* valid  = (unsigned char*)(ws + off); off += NCAMS * NQ;

  hipLaunchKernelGGL(k_prep, dim3(1280 + NQ), dim3(256), 0, stream,
                     Wv, Woff, Wattn, Wout, query, WT, WTq, WoutT, qbf);
  hipLaunchKernelGGL(k_valproj, dim3((MVAL + 127) / 128), dim3(512), 0, stream,
                     key_feats, WT, bv, val);
  hipLaunchKernelGGL(k_gemm_small, dim3((NQ + 127) / 128, 6), dim3(256), 0, stream,
                     qbf, WTq, boff, battn, 512, (const float*)nullptr, OFFLOG, NQ, 768, 0);
  hipLaunchKernelGGL(k_maskvalid, dim3((NCAMS * NQ + 255) / 256), dim3(256), 0, stream,
                     mask, valid);
  hipLaunchKernelGGL(k_sample, dim3(NQ), dim3(256), 0, stream,
                     val, OFFLOG, ref, valid, slots);
  hipLaunchKernelGGL(k_gemm_small, dim3((NQ + 127) / 128, 2), dim3(256), 0, stream,
                     slots, WoutT, bout, bout, 1 << 30, query, out, NQ, 256, 1);
}

// Round 9
// 183.109 us; speedup vs baseline: 2.2552x; 1.0588x over previous
//
#include <hip/hip_runtime.h>
#include <hip/hip_bf16.h>
#include <cstdint>

#define NCAMS 6
#define NQ 2500
#define EMBED 256
#define HEADS 8
#define DHEAD 32
#define LTOT 19560
#define MVAL (NCAMS * LTOT) /* 117360 */

typedef __attribute__((ext_vector_type(8))) short bf16x8;
typedef __attribute__((ext_vector_type(4))) float f32x4;

__device__ __forceinline__ unsigned short f2bf(float f) {
  unsigned u = __float_as_uint(f);
  return (unsigned short)((u + 0x7fffu + ((u >> 16) & 1u)) >> 16);
}
__device__ __forceinline__ unsigned short bfbits(float x) {
  __hip_bfloat16 h = __float2bfloat16(x);
  return __builtin_bit_cast(unsigned short, h);
}

// ---------------------------------------------------------------------------
// Kernel P: all weight transposes -> bf16, plus query -> bf16.
// ---------------------------------------------------------------------------
__global__ __launch_bounds__(256) void k_prep(
    const float* __restrict__ Wv, const float* __restrict__ Woff,
    const float* __restrict__ Wattn, const float* __restrict__ Wout,
    const float* __restrict__ query,
    unsigned short* __restrict__ WT, unsigned short* __restrict__ WTq,
    unsigned short* __restrict__ WoutT, unsigned short* __restrict__ qbf)
{
  const int b = blockIdx.x, t = threadIdx.x;
  if (b < 256) {
    WT[(size_t)b * 256 + t] = f2bf(Wv[(size_t)t * 256 + b]);
  } else if (b < 768) {
    int c = b - 256;
    WTq[(size_t)c * 256 + t] = f2bf(Woff[(size_t)t * 512 + c]);
  } else if (b < 1024) {
    int c = b - 768;
    WTq[(size_t)(512 + c) * 256 + t] = f2bf(Wattn[(size_t)t * 256 + c]);
  } else if (b < 1280) {
    int c = b - 1024;
    WoutT[(size_t)c * 256 + t] = f2bf(Wout[(size_t)t * 256 + c]);
  } else {
    int q = b - 1280;
    qbf[(size_t)q * 256 + t] = f2bf(query[(size_t)q * 256 + t]);
  }
}

// ---------------------------------------------------------------------------
// Kernel A (v5): val = bf16( key_feats @ W_value + b_value )
// Round-8 staged pipeline + LDS-transpose epilogue for FULL-SECTOR stores:
// swapped-operand fragments (lane = row laneM, 4 consecutive cols) written
// to a per-wave LDS tile (pitch 36 shorts = 72B, 8B-aligned uint2 writes),
// read back as uint4 -> 64B-aligned sector stores. Reuses As/Bs LDS after
// one barrier; two col-halves reuse the same region (WAR safe: global-store
// lgkm wait precedes next ds_write).
// launch_bounds MUST stay (512,2): higher min-waves caps VGPR->spill (r7).
// ---------------------------------------------------------------------------
__global__ __launch_bounds__(512, 2) void k_valproj(
    const float* __restrict__ A,            // (117360, 256) f32
    const unsigned short* __restrict__ WT,  // (256 cols, 256 k) bf16
    const float* __restrict__ bv,           // (256,)
    unsigned short* __restrict__ val)       // (117360, 256) bf16
{
  __shared__ unsigned short smem[128 * 64 + 256 * 64]; // 49152 B
  unsigned short* As = smem;              // [128][64] swizzled
  unsigned short* Bs = smem + 128 * 64;   // [256][64] swizzled
  const int t = threadIdx.x;
  const int lane = t & 63;
  const int wid = t >> 6;
  const int wm = wid >> 2, wn = wid & 3;
  const int laneM = lane & 15, kGrp = lane >> 4;
  const int bm = blockIdx.x * 128;

  const int aG = t & 15, aR0 = t >> 4;  // A: 16 float4-groups/row, 32 rows/pass
  const int bC = t & 7,  bR0 = t >> 3;  // B: 8 16B-chunks/row, 64 rows/pass

  float4 aRegs[2][4];
  uint4  bRegs[2][4];
  f32x4  acc[4][4];
#pragma unroll
  for (int m = 0; m < 4; ++m)
#pragma unroll
    for (int n = 0; n < 4; ++n) acc[m][n] = {0.f, 0.f, 0.f, 0.f};

  // prologue: load K-step 0
#pragma unroll
  for (int p = 0; p < 4; ++p) {
    int row = bm + aR0 + p * 32;
    aRegs[0][p] = (row < MVAL) ? *(const float4*)&A[(size_t)row * 256 + aG * 4]
                               : make_float4(0.f, 0.f, 0.f, 0.f);
    bRegs[0][p] = *(const uint4*)&WT[(size_t)(bR0 + p * 64) * 256 + bC * 8];
  }

#pragma unroll
  for (int kk = 0; kk < 4; ++kk) {
    const int cur = kk & 1, nxt = cur ^ 1;
    if (kk) __syncthreads();
    // ---- store staged regs -> LDS (convert A to bf16), swizzled ----
#pragma unroll
    for (int p = 0; p < 4; ++p) {
      int row = aR0 + p * 32;
      int elem = row * 64 + (((aG >> 1) ^ (row & 7)) << 3) + (aG & 1) * 4;
      float4 a = aRegs[cur][p];
      uint2 u;
      u.x = (unsigned)f2bf(a.x) | ((unsigned)f2bf(a.y) << 16);
      u.y = (unsigned)f2bf(a.z) | ((unsigned)f2bf(a.w) << 16);
      *(uint2*)&As[elem] = u;
    }
#pragma unroll
    for (int p = 0; p < 4; ++p) {
      int row = bR0 + p * 64;
      int elem = row * 64 + ((bC ^ (row & 7)) << 3);
      *(uint4*)&Bs[elem] = bRegs[cur][p];
    }
    __syncthreads();
    // ---- prefetch next K-step ----
    if (kk < 3) {
      const int kn = (kk + 1) * 64;
#pragma unroll
      for (int p = 0; p < 4; ++p) {
        int row = bm + aR0 + p * 32;
        aRegs[nxt][p] = (row < MVAL)
            ? *(const float4*)&A[(size_t)row * 256 + kn + aG * 4]
            : make_float4(0.f, 0.f, 0.f, 0.f);
        bRegs[nxt][p] = *(const uint4*)&WT[(size_t)(bR0 + p * 64) * 256 + kn + bC * 8];
      }
    }
    // ---- MFMA on current LDS tiles (swapped operand order) ----
#pragma unroll
    for (int ks = 0; ks < 2; ++ks) {
      bf16x8 af[4], bfr[4];
#pragma unroll
      for (int m = 0; m < 4; ++m) {
        int row = wm * 64 + m * 16 + laneM;
        af[m] = *(bf16x8*)&As[row * 64 + (((ks * 4 + kGrp) ^ (row & 7)) << 3)];
      }
#pragma unroll
      for (int n = 0; n < 4; ++n) {
        int row = wn * 64 + n * 16 + laneM;
        bfr[n] = *(bf16x8*)&Bs[row * 64 + (((ks * 4 + kGrp) ^ (row & 7)) << 3)];
      }
#pragma unroll
      for (int m = 0; m < 4; ++m)
#pragma unroll
        for (int n = 0; n < 4; ++n)
          acc[m][n] = __builtin_amdgcn_mfma_f32_16x16x32_bf16(bfr[n], af[m], acc[m][n], 0, 0, 0);
    }
  }

  // ---- epilogue: per-wave LDS transpose -> full-sector coalesced stores ----
  float4 bb4[4];
#pragma unroll
  for (int n = 0; n < 4; ++n)
    bb4[n] = *(const float4*)&bv[wn * 64 + n * 16 + kGrp * 4];

  __syncthreads();  // all waves finished reading As/Bs
  unsigned short* tlw = smem + wid * (64 * 36);  // per-wave [64][36] (72B pitch)

#pragma unroll
  for (int half = 0; half < 2; ++half) {
#pragma unroll
    for (int m = 0; m < 4; ++m) {
#pragma unroll
      for (int nn = 0; nn < 2; ++nn) {
        int n = half * 2 + nn;
        uint2 u;
        u.x = (unsigned)bfbits(acc[m][n][0] + bb4[n].x) |
              ((unsigned)bfbits(acc[m][n][1] + bb4[n].y) << 16);
        u.y = (unsigned)bfbits(acc[m][n][2] + bb4[n].z) |
              ((unsigned)bfbits(acc[m][n][3] + bb4[n].w) << 16);
        *(uint2*)&tlw[(m * 16 + laneM) * 36 + nn * 16 + kGrp * 4] = u;
      }
    }
#pragma unroll
    for (int i = 0; i < 4; ++i) {
      int rowl = i * 16 + (lane >> 2);
      int row = bm + wm * 64 + rowl;
      uint4 v = *(const uint4*)&tlw[rowl * 36 + (lane & 3) * 8];
      if (row < MVAL)
        *(uint4*)&val[(size_t)row * 256 + wn * 64 + half * 32 + (lane & 3) * 8] = v;
    }
  }
}

// ---------------------------------------------------------------------------
// Kernel G: generic small-M GEMM.  C(M,N) = A_bf16(M,256) @ BT_bf16(N,256)^T
//           + bias (split ba/bb at bsplit) [+ resid(M,256) if withResid]
// ---------------------------------------------------------------------------
__global__ __launch_bounds__(256, 2) void k_gemm_small(
    const unsigned short* __restrict__ A,
    const unsigned short* __restrict__ BT,
    const float* __restrict__ ba, const float* __restrict__ bb, int bsplit,
    const float* __restrict__ resid,
    float* __restrict__ C, int M, int N, int withResid)
{
  __shared__ unsigned short As[128 * 64];
  __shared__ unsigned short Bs[128 * 64];
  const int t = threadIdx.x;
  const int lane = t & 63;
  const int wid = t >> 6;
  const int wm = wid >> 1, wn = wid & 1;
  const int laneM = lane & 15, kGrp = lane >> 4;
  const int bm = blockIdx.x * 128;
  const int bn = blockIdx.y * 128;

  const int aC = t & 7, aR0 = t >> 3;

  uint4 aRegs[2][4];
  uint4 bRegs[2][4];
  f32x4 acc[4][4];
#pragma unroll
  for (int m = 0; m < 4; ++m)
#pragma unroll
    for (int n = 0; n < 4; ++n) acc[m][n] = {0.f, 0.f, 0.f, 0.f};

#pragma unroll
  for (int p = 0; p < 4; ++p) {
    int arow = bm + aR0 + p * 32;
    aRegs[0][p] = (arow < M) ? *(const uint4*)&A[(size_t)arow * 256 + aC * 8]
                             : make_uint4(0u, 0u, 0u, 0u);
    bRegs[0][p] = *(const uint4*)&BT[(size_t)(bn + aR0 + p * 32) * 256 + aC * 8];
  }

#pragma unroll
  for (int kk = 0; kk < 4; ++kk) {
    const int cur = kk & 1, nxt = cur ^ 1;
    if (kk) __syncthreads();
#pragma unroll
    for (int p = 0; p < 4; ++p) {
      int row = aR0 + p * 32;
      int elem = row * 64 + ((aC ^ (row & 7)) << 3);
      *(uint4*)&As[elem] = aRegs[cur][p];
      *(uint4*)&Bs[elem] = bRegs[cur][p];
    }
    __syncthreads();
    if (kk < 3) {
      const int kn = (kk + 1) * 64;
#pragma unroll
      for (int p = 0; p < 4; ++p) {
        int arow = bm + aR0 + p * 32;
        aRegs[nxt][p] = (arow < M)
            ? *(const uint4*)&A[(size_t)arow * 256 + kn + aC * 8]
            : make_uint4(0u, 0u, 0u, 0u);
        bRegs[nxt][p] = *(const uint4*)&BT[(size_t)(bn + aR0 + p * 32) * 256 + kn + aC * 8];
      }
    }
#pragma unroll
    for (int ks = 0; ks < 2; ++ks) {
      bf16x8 af[4], bfr[4];
#pragma unroll
      for (int m = 0; m < 4; ++m) {
        int row = wm * 64 + m * 16 + laneM;
        af[m] = *(bf16x8*)&As[row * 64 + (((ks * 4 + kGrp) ^ (row & 7)) << 3)];
      }
#pragma unroll
      for (int n = 0; n < 4; ++n) {
        int row = wn * 64 + n * 16 + laneM;
        bfr[n] = *(bf16x8*)&Bs[row * 64 + (((ks * 4 + kGrp) ^ (row & 7)) << 3)];
      }
#pragma unroll
      for (int m = 0; m < 4; ++m)
#pragma unroll
        for (int n = 0; n < 4; ++n)
          acc[m][n] = __builtin_amdgcn_mfma_f32_16x16x32_bf16(af[m], bfr[n], acc[m][n], 0, 0, 0);
    }
  }

  float bvn[4];
#pragma unroll
  for (int n = 0; n < 4; ++n) {
    int col = bn + wn * 64 + n * 16 + laneM;
    bvn[n] = (col < bsplit) ? ba[col] : bb[col - bsplit];
  }
#pragma unroll
  for (int m = 0; m < 4; ++m) {
#pragma unroll
    for (int r = 0; r < 4; ++r) {
      int row = bm + wm * 64 + m * 16 + kGrp * 4 + r;
      if (row < M) {
#pragma unroll
        for (int n = 0; n < 4; ++n) {
          int col = bn + wn * 64 + n * 16 + laneM;
          float v = acc[m][n][r] + bvn[n];
          if (withResid) v += resid[(size_t)row * 256 + col];
          C[(size_t)row * N + col] = v;
        }
      }
    }
  }
}

// ---------------------------------------------------------------------------
// Kernel M: bev_mask -> valid[6*2500], on-device dtype detect (int32 vs u8).
// ---------------------------------------------------------------------------
__global__ __launch_bounds__(256) void k_maskvalid(
    const unsigned char* __restrict__ MSK,
    unsigned char* __restrict__ valid)
{
  __shared__ int s_u8;
  const int t = threadIdx.x;
  if (t == 0) s_u8 = 0;
  __syncthreads();
  if ((t & 3) && MSK[t]) atomicOr(&s_u8, 1);
  __syncthreads();
  const int isU8 = s_u8;

  const int i = blockIdx.x * 256 + t;
  if (i < NCAMS * NQ) {
    int any;
    if (isU8) {
      const unsigned char* p = MSK + (size_t)i * 4;
      any = p[0] | p[1] | p[2] | p[3];
    } else {
      const int* p = (const int*)MSK + (size_t)i * 4;
      any = p[0] | p[1] | p[2] | p[3];
    }
    valid[i] = any ? 1 : 0;
  }
}

// ---------------------------------------------------------------------------
// Kernel C (two-phase sampling).  OFFLOG row = [OFF(512) | LOG(256)].
// ---------------------------------------------------------------------------
__global__ __launch_bounds__(256) void k_sample(
    const unsigned short* __restrict__ val,   // (117360, 256) bf16
    const float* __restrict__ OFFLOG,         // (2500, 768)
    const float* __restrict__ REF,            // (6,1,2500,4,2)
    const unsigned char* __restrict__ valid,  // (6,2500)
    unsigned short* __restrict__ slots)       // (2500,256) bf16
{
  __shared__ int2  s_pack[4][NCAMS][256];
  __shared__ float s_off[512];
  __shared__ float s_ref[48];
  __shared__ int   s_valid[6];

  const int q = blockIdx.x;
  const int t = threadIdx.x;

  s_off[t]       = OFFLOG[(size_t)q * 768 + t];
  s_off[t + 256] = OFFLOG[(size_t)q * 768 + 256 + t];
  if (t < 48) s_ref[t] = REF[(size_t)(t >> 3) * (NQ * 8) + (size_t)q * 8 + (t & 7)];
  if (t < 6) s_valid[t] = valid[(size_t)t * NQ + q];

  float logit = OFFLOG[(size_t)q * 768 + 512 + t];
  float m = logit;
#pragma unroll
  for (int o = 16; o > 0; o >>= 1) m = fmaxf(m, __shfl_xor(m, o, 32));
  float e = __expf(logit - m);
  float s = e;
#pragma unroll
  for (int o = 16; o > 0; o >>= 1) s += __shfl_xor(s, o, 32);
  const float a = e / s;
  __syncthreads();

  {
    const int h1 = t >> 5, lp = t & 31, lvl = lp >> 3, p = lp & 7, z = p & 3;
    const int WW = 160 >> lvl;
    const int HH = (lvl < 3) ? (92 >> lvl) : 12;
    const int S  = (lvl == 0) ? 0 : (lvl == 1) ? 14720 : (lvl == 2) ? 18400 : 19320;
    const float Wf = (float)WW, Hf = (float)HH;
    const float ox = s_off[h1 * 64 + lp * 2];
    const float oy = s_off[h1 * 64 + lp * 2 + 1];
#pragma unroll 1
    for (int cam = 0; cam < NCAMS; ++cam) {
      if (!s_valid[cam]) continue;
      float rx = s_ref[cam * 8 + z * 2];
      float ry = s_ref[cam * 8 + z * 2 + 1];
      float x = rx * Wf + ox - 0.5f;
      float y = ry * Hf + oy - 0.5f;
      float x0f = floorf(x), y0f = floorf(y);
      float fx = x - x0f, fy = y - y0f;
      int x0 = (int)x0f, y0 = (int)y0f;
      int base = cam * LTOT + S;
#pragma unroll
      for (int dy = 0; dy < 2; ++dy) {
        int yi = y0 + dy;
        float wy = dy ? fy : 1.f - fy;
        int yc = min(max(yi, 0), HH - 1);
        bool vy = (yi >= 0) && (yi < HH);
#pragma unroll
        for (int dx = 0; dx < 2; ++dx) {
          int xi = x0 + dx;
          float wx = dx ? fx : 1.f - fx;
          int xc = min(max(xi, 0), WW - 1);
          bool vv = vy && (xi >= 0) && (xi < WW);
          float wgt = vv ? wx * wy * a : 0.f;
          int addr = (base + yc * WW + xc) * 512;
          s_pack[dy * 2 + dx][cam][t] = make_int2(addr, __float_as_int(wgt));
        }
      }
    }
  }
  __syncthreads();

  const int h = t >> 5, pp = (t >> 3) & 3, l8 = t & 7;
  const unsigned dconst = (unsigned)(h * 64 + l8 * 8);
  const char* vb = (const char*)val;
  int nvalid = s_valid[0] + s_valid[1] + s_valid[2] + s_valid[3] + s_valid[4] + s_valid[5];
  float inv = 1.f / fmaxf((float)nvalid, 1.f);

  f32x4 acc = {0.f, 0.f, 0.f, 0.f};
#pragma unroll 1
  for (int cam = 0; cam < NCAMS; ++cam) {
    if (!s_valid[cam]) continue;
#pragma unroll
    for (int it = 0; it < 8; ++it) {
      const int idx = h * 32 + pp + it * 4;
      int2 pk0 = s_pack[0][cam][idx];
      int2 pk1 = s_pack[1][cam][idx];
      int2 pk2 = s_pack[2][cam][idx];
      int2 pk3 = s_pack[3][cam][idx];
      uint2 v0 = *(const uint2*)(vb + (size_t)((unsigned)pk0.x + dconst));
      uint2 v1 = *(const uint2*)(vb + (size_t)((unsigned)pk1.x + dconst));
      uint2 v2 = *(const uint2*)(vb + (size_t)((unsigned)pk2.x + dconst));
      uint2 v3 = *(const uint2*)(vb + (size_t)((unsigned)pk3.x + dconst));
      float w0 = __int_as_float(pk0.y), w1 = __int_as_float(pk1.y);
      float w2 = __int_as_float(pk2.y), w3 = __int_as_float(pk3.y);
      acc[0] += w0 * __uint_as_float(v0.x << 16);
      acc[1] += w0 * __uint_as_float(v0.x & 0xffff0000u);
      acc[2] += w0 * __uint_as_float(v0.y << 16);
      acc[3] += w0 * __uint_as_float(v0.y & 0xffff0000u);
      acc[0] += w1 * __uint_as_float(v1.x << 16);
      acc[1] += w1 * __uint_as_float(v1.x & 0xffff0000u);
      acc[2] += w1 * __uint_as_float(v1.y << 16);
      acc[3] += w1 * __uint_as_float(v1.y & 0xffff0000u);
      acc[0] += w2 * __uint_as_float(v2.x << 16);
      acc[1] += w2 * __uint_as_float(v2.x & 0xffff0000u);
      acc[2] += w2 * __uint_as_float(v2.y << 16);
      acc[3] += w2 * __uint_as_float(v2.y & 0xffff0000u);
      acc[0] += w3 * __uint_as_float(v3.x << 16);
      acc[1] += w3 * __uint_as_float(v3.x & 0xffff0000u);
      acc[2] += w3 * __uint_as_float(v3.y << 16);
      acc[3] += w3 * __uint_as_float(v3.y & 0xffff0000u);
    }
  }

#pragma unroll
  for (int i = 0; i < 4; ++i) {
    acc[i] += __shfl_xor(acc[i], 8);
    acc[i] += __shfl_xor(acc[i], 16);
  }
  if (pp == 0) {
    uint2 r;
    r.x = (unsigned)f2bf(acc[0] * inv) | ((unsigned)f2bf(acc[1] * inv) << 16);
    r.y = (unsigned)f2bf(acc[2] * inv) | ((unsigned)f2bf(acc[3] * inv) << 16);
    *(uint2*)&slots[(size_t)q * 256 + h * 32 + l8 * 4] = r;
  }
}

// ---------------------------------------------------------------------------
extern "C" void kernel_launch(void* const* d_in, const int* in_sizes, int n_in,
                              void* d_out, int out_size, void* d_ws, size_t ws_size,
                              hipStream_t stream) {
  const float* query     = (const float*)d_in[0];
  const float* key_feats = (const float*)d_in[1];
  const float* ref       = (const float*)d_in[2];
  const unsigned char* mask = (const unsigned char*)d_in[3];
  // d_in[4] = spatial_shapes (compile-time constants)
  const float* Wv    = (const float*)d_in[5];
  const float* bv    = (const float*)d_in[6];
  const float* Woff  = (const float*)d_in[7];
  const float* boff  = (const float*)d_in[8];
  const float* Wattn = (const float*)d_in[9];
  const float* battn = (const float*)d_in[10];
  const float* Wout  = (const float*)d_in[11];
  const float* bout  = (const float*)d_in[12];
  float* out = (float*)d_out;

  char* ws = (char*)d_ws;
  size_t off = 0;
  unsigned short* val   = (unsigned short*)(ws + off); off += (size_t)MVAL * 256 * 2;
  unsigned short* WT    = (unsigned short*)(ws + off); off += 256 * 256 * 2;
  unsigned short* WTq   = (unsigned short*)(ws + off); off += 768 * 256 * 2;
  unsigned short* WoutT = (unsigned short*)(ws + off); off += 256 * 256 * 2;
  unsigned short* qbf   = (unsigned short*)(ws + off); off += (size_t)NQ * 256 * 2;
  float* OFFLOG = (float*)(ws + off); off += (size_t)NQ * 768 * 4;
  unsigned short* slots = (unsigned short*)(ws + off); off += (size_t)NQ * 256 * 2;
  unsigned char* valid  = (unsigned char*)(ws + off); off += NCAMS * NQ;

  hipLaunchKernelGGL(k_prep, dim3(1280 + NQ), dim3(256), 0, stream,
                     Wv, Woff, Wattn, Wout, query, WT, WTq, WoutT, qbf);
  hipLaunchKernelGGL(k_valproj, dim3((MVAL + 127) / 128), dim3(512), 0, stream,
                     key_feats, WT, bv, val);
  hipLaunchKernelGGL(k_gemm_small, dim3((NQ + 127) / 128, 6), dim3(256), 0, stream,
                     qbf, WTq, boff, battn, 512, (const float*)nullptr, OFFLOG, NQ, 768, 0);
  hipLaunchKernelGGL(k_maskvalid, dim3((NCAMS * NQ + 255) / 256), dim3(256), 0, stream,
                     mask, valid);
  hipLaunchKernelGGL(k_sample, dim3(NQ), dim3(256), 0, stream,
                     val, OFFLOG, ref, valid, slots);
  hipLaunchKernelGGL(k_gemm_small, dim3((NQ + 127) / 128, 2), dim3(256), 0, stream,
                     slots, WoutT, bout, bout, 1 << 30, query, out, NQ, 256, 1);
}

// Round 10
// 168.807 us; speedup vs baseline: 2.4463x; 1.0847x over previous
//
#include <hip/hip_runtime.h>
#include <hip/hip_bf16.h>
#include <cstdint>

#define NCAMS 6
#define NQ 2500
#define EMBED 256
#define HEADS 8
#define DHEAD 32
#define LTOT 19560
#define MVAL (NCAMS * LTOT) /* 117360 */

typedef __attribute__((ext_vector_type(8))) short bf16x8;
typedef __attribute__((ext_vector_type(4))) float f32x4;

__device__ __forceinline__ unsigned short f2bf(float f) {
  unsigned u = __float_as_uint(f);
  return (unsigned short)((u + 0x7fffu + ((u >> 16) & 1u)) >> 16);
}
__device__ __forceinline__ unsigned short bfbits(float x) {
  __hip_bfloat16 h = __float2bfloat16(x);
  return __builtin_bit_cast(unsigned short, h);
}
__device__ __forceinline__ void gl16(const unsigned short* g, unsigned short* l) {
  __builtin_amdgcn_global_load_lds(
      (const __attribute__((address_space(1))) unsigned int*)g,
      (__attribute__((address_space(3))) unsigned int*)l, 16, 0, 0);
}

// ---------------------------------------------------------------------------
// Kernel P: all weight transposes -> bf16, plus query -> bf16.
// ---------------------------------------------------------------------------
__global__ __launch_bounds__(256) void k_prep(
    const float* __restrict__ Wv, const float* __restrict__ Woff,
    const float* __restrict__ Wattn, const float* __restrict__ Wout,
    const float* __restrict__ query,
    unsigned short* __restrict__ WT, unsigned short* __restrict__ WTq,
    unsigned short* __restrict__ WoutT, unsigned short* __restrict__ qbf)
{
  const int b = blockIdx.x, t = threadIdx.x;
  if (b < 256) {
    WT[(size_t)b * 256 + t] = f2bf(Wv[(size_t)t * 256 + b]);
  } else if (b < 768) {
    int c = b - 256;
    WTq[(size_t)c * 256 + t] = f2bf(Woff[(size_t)t * 512 + c]);
  } else if (b < 1024) {
    int c = b - 768;
    WTq[(size_t)(512 + c) * 256 + t] = f2bf(Wattn[(size_t)t * 256 + c]);
  } else if (b < 1280) {
    int c = b - 1024;
    WoutT[(size_t)c * 256 + t] = f2bf(Wout[(size_t)t * 256 + c]);
  } else {
    int q = b - 1280;
    qbf[(size_t)q * 256 + t] = f2bf(query[(size_t)q * 256 + t]);
  }
}

// ---------------------------------------------------------------------------
// Kernel F: key_feats f32 -> bf16, streamed (written into the val buffer;
// k_valproj then reads it in-place: each block reads only the rows it later
// overwrites, so this is race-free and replay-deterministic).
// ---------------------------------------------------------------------------
__global__ __launch_bounds__(256) void k_abf(
    const float* __restrict__ A, unsigned short* __restrict__ Abf)
{
  const size_t N8 = (size_t)MVAL * 256 / 8;
  for (size_t i = (size_t)blockIdx.x * 256 + threadIdx.x; i < N8;
       i += (size_t)gridDim.x * 256) {
    float4 x = *(const float4*)&A[i * 8];
    float4 y = *(const float4*)&A[i * 8 + 4];
    uint4 u;
    u.x = (unsigned)f2bf(x.x) | ((unsigned)f2bf(x.y) << 16);
    u.y = (unsigned)f2bf(x.z) | ((unsigned)f2bf(x.w) << 16);
    u.z = (unsigned)f2bf(y.x) | ((unsigned)f2bf(y.y) << 16);
    u.w = (unsigned)f2bf(y.z) | ((unsigned)f2bf(y.w) << 16);
    *(uint4*)&Abf[i * 8] = u;
  }
}

// ---------------------------------------------------------------------------
// Kernel A (v6): val = bf16( Abf @ W_value + b_value ), all-bf16, staged via
// global_load_lds width=16 (async, no VGPR round trip). Linear LDS dest +
// pre-swizzled GLOBAL source (chunk ^= row&7); fragment reads apply the same
// XOR (involution). 512 thr, 8 waves 2Mx4N, BM=128, BN=256, BK=64.
// LDS 48KB -> 3 blocks/CU. Epilogue: per-wave LDS transpose reusing staging
// smem, 128B-contiguous sector stores (r6-proven: WRITE_SIZE ideal).
// launch_bounds MUST stay (512,2): larger min-waves caps VGPR->spill (r7).
// ---------------------------------------------------------------------------
__global__ __launch_bounds__(512, 2) void k_valproj(
    const unsigned short* __restrict__ Abf,  // (117360, 256) bf16 (== val!)
    const unsigned short* __restrict__ WT,   // (256 cols, 256 k) bf16
    const float* __restrict__ bv,            // (256,)
    unsigned short* __restrict__ val)        // (117360, 256) bf16
{
  __shared__ unsigned short smem[128 * 64 + 256 * 64]; // 48 KB
  unsigned short* As = smem;              // [128][64] (swizzled contents)
  unsigned short* Bs = smem + 128 * 64;   // [256][64]
  const int t = threadIdx.x;
  const int lane = t & 63;
  const int wid = t >> 6;
  const int wm = wid >> 2, wn = wid & 3;
  const int laneM = lane & 15, kGrp = lane >> 4;
  const int bm = blockIdx.x * 128;

  // staging coordinates: thread covers 16B chunk (sub, chk) of each 64-row panel
  const int sub = t >> 3;            // 0..63
  const int swz = (t & 7) ^ (sub & 7);
  const unsigned short* aS0 = Abf + (size_t)min(bm + sub, MVAL - 1) * 256 + swz * 8;
  const unsigned short* aS1 = Abf + (size_t)min(bm + 64 + sub, MVAL - 1) * 256 + swz * 8;
  const unsigned short* bS0 = WT + (size_t)(sub) * 256 + swz * 8;
  const unsigned short* bS1 = WT + (size_t)(64 + sub) * 256 + swz * 8;
  const unsigned short* bS2 = WT + (size_t)(128 + sub) * 256 + swz * 8;
  const unsigned short* bS3 = WT + (size_t)(192 + sub) * 256 + swz * 8;

  f32x4 acc[4][4];
#pragma unroll
  for (int m = 0; m < 4; ++m)
#pragma unroll
    for (int n = 0; n < 4; ++n) acc[m][n] = {0.f, 0.f, 0.f, 0.f};

#pragma unroll 1
  for (int kk = 0; kk < 4; ++kk) {
    if (kk) __syncthreads();   // previous compute done reading LDS
    const int ko = kk * 64;
    gl16(aS0 + ko, As + wid * 512);
    gl16(aS1 + ko, As + 4096 + wid * 512);
    gl16(bS0 + ko, Bs + wid * 512);
    gl16(bS1 + ko, Bs + 4096 + wid * 512);
    gl16(bS2 + ko, Bs + 8192 + wid * 512);
    gl16(bS3 + ko, Bs + 12288 + wid * 512);
    __syncthreads();           // drains vmcnt -> staged data visible

#pragma unroll
    for (int ks = 0; ks < 2; ++ks) {
      bf16x8 af[4], bfr[4];
#pragma unroll
      for (int m = 0; m < 4; ++m) {
        int row = wm * 64 + m * 16 + laneM;
        af[m] = *(bf16x8*)&As[row * 64 + (((ks * 4 + kGrp) ^ (row & 7)) << 3)];
      }
#pragma unroll
      for (int n = 0; n < 4; ++n) {
        int row = wn * 64 + n * 16 + laneM;
        bfr[n] = *(bf16x8*)&Bs[row * 64 + (((ks * 4 + kGrp) ^ (row & 7)) << 3)];
      }
#pragma unroll
      for (int m = 0; m < 4; ++m)
#pragma unroll
        for (int n = 0; n < 4; ++n)
          acc[m][n] = __builtin_amdgcn_mfma_f32_16x16x32_bf16(bfr[n], af[m], acc[m][n], 0, 0, 0);
    }
  }

  // ---- epilogue: swapped C/D layout (lane = row laneM, cols kGrp*4+r).
  // Per-wave LDS transpose (reuses staging smem) -> 128B contiguous stores.
  float4 bb4[4];
#pragma unroll
  for (int n = 0; n < 4; ++n)
    bb4[n] = *(const float4*)&bv[wn * 64 + n * 16 + kGrp * 4];

  __syncthreads();  // all waves done reading As/Bs
  unsigned short* tlw = smem + wid * (32 * 72);  // per-wave [32][72]

#pragma unroll
  for (int hm = 0; hm < 2; ++hm) {
#pragma unroll
    for (int mm = 0; mm < 2; ++mm) {
      const int m = hm * 2 + mm;
#pragma unroll
      for (int n = 0; n < 4; ++n) {
        uint2 u;
        u.x = (unsigned)bfbits(acc[m][n][0] + bb4[n].x) |
              ((unsigned)bfbits(acc[m][n][1] + bb4[n].y) << 16);
        u.y = (unsigned)bfbits(acc[m][n][2] + bb4[n].z) |
              ((unsigned)bfbits(acc[m][n][3] + bb4[n].w) << 16);
        *(uint2*)&tlw[(mm * 16 + laneM) * 72 + n * 16 + kGrp * 4] = u;
      }
    }
#pragma unroll
    for (int i = 0; i < 4; ++i) {
      const int rowl = i * 8 + (lane >> 3);
      const int c8 = lane & 7;
      uint4 v = *(const uint4*)&tlw[rowl * 72 + c8 * 8];
      const int row = bm + wm * 64 + hm * 32 + rowl;
      if (row < MVAL)
        *(uint4*)&val[(size_t)row * 256 + wn * 64 + c8 * 8] = v;
    }
  }
}

// ---------------------------------------------------------------------------
// Kernel G: generic small-M GEMM.  C(M,N) = A_bf16(M,256) @ BT_bf16(N,256)^T
//           + bias (split ba/bb at bsplit) [+ resid(M,256) if withResid]
// ---------------------------------------------------------------------------
__global__ __launch_bounds__(256, 2) void k_gemm_small(
    const unsigned short* __restrict__ A,
    const unsigned short* __restrict__ BT,
    const float* __restrict__ ba, const float* __restrict__ bb, int bsplit,
    const float* __restrict__ resid,
    float* __restrict__ C, int M, int N, int withResid)
{
  __shared__ unsigned short As[128 * 64];
  __shared__ unsigned short Bs[128 * 64];
  const int t = threadIdx.x;
  const int lane = t & 63;
  const int wid = t >> 6;
  const int wm = wid >> 1, wn = wid & 1;
  const int laneM = lane & 15, kGrp = lane >> 4;
  const int bm = blockIdx.x * 128;
  const int bn = blockIdx.y * 128;

  const int aC = t & 7, aR0 = t >> 3;

  uint4 aRegs[2][4];
  uint4 bRegs[2][4];
  f32x4 acc[4][4];
#pragma unroll
  for (int m = 0; m < 4; ++m)
#pragma unroll
    for (int n = 0; n < 4; ++n) acc[m][n] = {0.f, 0.f, 0.f, 0.f};

#pragma unroll
  for (int p = 0; p < 4; ++p) {
    int arow = bm + aR0 + p * 32;
    aRegs[0][p] = (arow < M) ? *(const uint4*)&A[(size_t)arow * 256 + aC * 8]
                             : make_uint4(0u, 0u, 0u, 0u);
    bRegs[0][p] = *(const uint4*)&BT[(size_t)(bn + aR0 + p * 32) * 256 + aC * 8];
  }

#pragma unroll
  for (int kk = 0; kk < 4; ++kk) {
    const int cur = kk & 1, nxt = cur ^ 1;
    if (kk) __syncthreads();
#pragma unroll
    for (int p = 0; p < 4; ++p) {
      int row = aR0 + p * 32;
      int elem = row * 64 + ((aC ^ (row & 7)) << 3);
      *(uint4*)&As[elem] = aRegs[cur][p];
      *(uint4*)&Bs[elem] = bRegs[cur][p];
    }
    __syncthreads();
    if (kk < 3) {
      const int kn = (kk + 1) * 64;
#pragma unroll
      for (int p = 0; p < 4; ++p) {
        int arow = bm + aR0 + p * 32;
        aRegs[nxt][p] = (arow < M)
            ? *(const uint4*)&A[(size_t)arow * 256 + kn + aC * 8]
            : make_uint4(0u, 0u, 0u, 0u);
        bRegs[nxt][p] = *(const uint4*)&BT[(size_t)(bn + aR0 + p * 32) * 256 + kn + aC * 8];
      }
    }
#pragma unroll
    for (int ks = 0; ks < 2; ++ks) {
      bf16x8 af[4], bfr[4];
#pragma unroll
      for (int m = 0; m < 4; ++m) {
        int row = wm * 64 + m * 16 + laneM;
        af[m] = *(bf16x8*)&As[row * 64 + (((ks * 4 + kGrp) ^ (row & 7)) << 3)];
      }
#pragma unroll
      for (int n = 0; n < 4; ++n) {
        int row = wn * 64 + n * 16 + laneM;
        bfr[n] = *(bf16x8*)&Bs[row * 64 + (((ks * 4 + kGrp) ^ (row & 7)) << 3)];
      }
#pragma unroll
      for (int m = 0; m < 4; ++m)
#pragma unroll
        for (int n = 0; n < 4; ++n)
          acc[m][n] = __builtin_amdgcn_mfma_f32_16x16x32_bf16(af[m], bfr[n], acc[m][n], 0, 0, 0);
    }
  }

  float bvn[4];
#pragma unroll
  for (int n = 0; n < 4; ++n) {
    int col = bn + wn * 64 + n * 16 + laneM;
    bvn[n] = (col < bsplit) ? ba[col] : bb[col - bsplit];
  }
#pragma unroll
  for (int m = 0; m < 4; ++m) {
#pragma unroll
    for (int r = 0; r < 4; ++r) {
      int row = bm + wm * 64 + m * 16 + kGrp * 4 + r;
      if (row < M) {
#pragma unroll
        for (int n = 0; n < 4; ++n) {
          int col = bn + wn * 64 + n * 16 + laneM;
          float v = acc[m][n][r] + bvn[n];
          if (withResid) v += resid[(size_t)row * 256 + col];
          C[(size_t)row * N + col] = v;
        }
      }
    }
  }
}

// ---------------------------------------------------------------------------
// Kernel M: bev_mask -> valid[6*2500], on-device dtype detect (int32 vs u8).
// ---------------------------------------------------------------------------
__global__ __launch_bounds__(256) void k_maskvalid(
    const unsigned char* __restrict__ MSK,
    unsigned char* __restrict__ valid)
{
  __shared__ int s_u8;
  const int t = threadIdx.x;
  if (t == 0) s_u8 = 0;
  __syncthreads();
  if ((t & 3) && MSK[t]) atomicOr(&s_u8, 1);
  __syncthreads();
  const int isU8 = s_u8;

  const int i = blockIdx.x * 256 + t;
  if (i < NCAMS * NQ) {
    int any;
    if (isU8) {
      const unsigned char* p = MSK + (size_t)i * 4;
      any = p[0] | p[1] | p[2] | p[3];
    } else {
      const int* p = (const int*)MSK + (size_t)i * 4;
      any = p[0] | p[1] | p[2] | p[3];
    }
    valid[i] = any ? 1 : 0;
  }
}

// ---------------------------------------------------------------------------
// Kernel C (two-phase sampling).  OFFLOG row = [OFF(512) | LOG(256)].
// ---------------------------------------------------------------------------
__global__ __launch_bounds__(256) void k_sample(
    const unsigned short* __restrict__ val,   // (117360, 256) bf16
    const float* __restrict__ OFFLOG,         // (2500, 768)
    const float* __restrict__ REF,            // (6,1,2500,4,2)
    const unsigned char* __restrict__ valid,  // (6,2500)
    unsigned short* __restrict__ slots)       // (2500,256) bf16
{
  __shared__ int2  s_pack[4][NCAMS][256];
  __shared__ float s_off[512];
  __shared__ float s_ref[48];
  __shared__ int   s_valid[6];

  const int q = blockIdx.x;
  const int t = threadIdx.x;

  s_off[t]       = OFFLOG[(size_t)q * 768 + t];
  s_off[t + 256] = OFFLOG[(size_t)q * 768 + 256 + t];
  if (t < 48) s_ref[t] = REF[(size_t)(t >> 3) * (NQ * 8) + (size_t)q * 8 + (t & 7)];
  if (t < 6) s_valid[t] = valid[(size_t)t * NQ + q];

  float logit = OFFLOG[(size_t)q * 768 + 512 + t];
  float m = logit;
#pragma unroll
  for (int o = 16; o > 0; o >>= 1) m = fmaxf(m, __shfl_xor(m, o, 32));
  float e = __expf(logit - m);
  float s = e;
#pragma unroll
  for (int o = 16; o > 0; o >>= 1) s += __shfl_xor(s, o, 32);
  const float a = e / s;
  __syncthreads();

  {
    const int h1 = t >> 5, lp = t & 31, lvl = lp >> 3, p = lp & 7, z = p & 3;
    const int WW = 160 >> lvl;
    const int HH = (lvl < 3) ? (92 >> lvl) : 12;
    const int S  = (lvl == 0) ? 0 : (lvl == 1) ? 14720 : (lvl == 2) ? 18400 : 19320;
    const float Wf = (float)WW, Hf = (float)HH;
    const float ox = s_off[h1 * 64 + lp * 2];
    const float oy = s_off[h1 * 64 + lp * 2 + 1];
#pragma unroll 1
    for (int cam = 0; cam < NCAMS; ++cam) {
      if (!s_valid[cam]) continue;
      float rx = s_ref[cam * 8 + z * 2];
      float ry = s_ref[cam * 8 + z * 2 + 1];
      float x = rx * Wf + ox - 0.5f;
      float y = ry * Hf + oy - 0.5f;
      float x0f = floorf(x), y0f = floorf(y);
      float fx = x - x0f, fy = y - y0f;
      int x0 = (int)x0f, y0 = (int)y0f;
      int base = cam * LTOT + S;
#pragma unroll
      for (int dy = 0; dy < 2; ++dy) {
        int yi = y0 + dy;
        float wy = dy ? fy : 1.f - fy;
        int yc = min(max(yi, 0), HH - 1);
        bool vy = (yi >= 0) && (yi < HH);
#pragma unroll
        for (int dx = 0; dx < 2; ++dx) {
          int xi = x0 + dx;
          float wx = dx ? fx : 1.f - fx;
          int xc = min(max(xi, 0), WW - 1);
          bool vv = vy && (xi >= 0) && (xi < WW);
          float wgt = vv ? wx * wy * a : 0.f;
          int addr = (base + yc * WW + xc) * 512;
          s_pack[dy * 2 + dx][cam][t] = make_int2(addr, __float_as_int(wgt));
        }
      }
    }
  }
  __syncthreads();

  const int h = t >> 5, pp = (t >> 3) & 3, l8 = t & 7;
  const unsigned dconst = (unsigned)(h * 64 + l8 * 8);
  const char* vb = (const char*)val;
  int nvalid = s_valid[0] + s_valid[1] + s_valid[2] + s_valid[3] + s_valid[4] + s_valid[5];
  float inv = 1.f / fmaxf((float)nvalid, 1.f);

  f32x4 acc = {0.f, 0.f, 0.f, 0.f};
#pragma unroll 1
  for (int cam = 0; cam < NCAMS; ++cam) {
    if (!s_valid[cam]) continue;
#pragma unroll
    for (int it = 0; it < 8; ++it) {
      const int idx = h * 32 + pp + it * 4;
      int2 pk0 = s_pack[0][cam][idx];
      int2 pk1 = s_pack[1][cam][idx];
      int2 pk2 = s_pack[2][cam][idx];
      int2 pk3 = s_pack[3][cam][idx];
      uint2 v0 = *(const uint2*)(vb + (size_t)((unsigned)pk0.x + dconst));
      uint2 v1 = *(const uint2*)(vb + (size_t)((unsigned)pk1.x + dconst));
      uint2 v2 = *(const uint2*)(vb + (size_t)((unsigned)pk2.x + dconst));
      uint2 v3 = *(const uint2*)(vb + (size_t)((unsigned)pk3.x + dconst));
      float w0 = __int_as_float(pk0.y), w1 = __int_as_float(pk1.y);
      float w2 = __int_as_float(pk2.y), w3 = __int_as_float(pk3.y);
      acc[0] += w0 * __uint_as_float(v0.x << 16);
      acc[1] += w0 * __uint_as_float(v0.x & 0xffff0000u);
      acc[2] += w0 * __uint_as_float(v0.y << 16);
      acc[3] += w0 * __uint_as_float(v0.y & 0xffff0000u);
      acc[0] += w1 * __uint_as_float(v1.x << 16);
      acc[1] += w1 * __uint_as_float(v1.x & 0xffff0000u);
      acc[2] += w1 * __uint_as_float(v1.y << 16);
      acc[3] += w1 * __uint_as_float(v1.y & 0xffff0000u);
      acc[0] += w2 * __uint_as_float(v2.x << 16);
      acc[1] += w2 * __uint_as_float(v2.x & 0xffff0000u);
      acc[2] += w2 * __uint_as_float(v2.y << 16);
      acc[3] += w2 * __uint_as_float(v2.y & 0xffff0000u);
      acc[0] += w3 * __uint_as_float(v3.x << 16);
      acc[1] += w3 * __uint_as_float(v3.x & 0xffff0000u);
      acc[2] += w3 * __uint_as_float(v3.y << 16);
      acc[3] += w3 * __uint_as_float(v3.y & 0xffff0000u);
    }
  }

#pragma unroll
  for (int i = 0; i < 4; ++i) {
    acc[i] += __shfl_xor(acc[i], 8);
    acc[i] += __shfl_xor(acc[i], 16);
  }
  if (pp == 0) {
    uint2 r;
    r.x = (unsigned)f2bf(acc[0] * inv) | ((unsigned)f2bf(acc[1] * inv) << 16);
    r.y = (unsigned)f2bf(acc[2] * inv) | ((unsigned)f2bf(acc[3] * inv) << 16);
    *(uint2*)&slots[(size_t)q * 256 + h * 32 + l8 * 4] = r;
  }
}

// ---------------------------------------------------------------------------
extern "C" void kernel_launch(void* const* d_in, const int* in_sizes, int n_in,
                              void* d_out, int out_size, void* d_ws, size_t ws_size,
                              hipStream_t stream) {
  const float* query     = (const float*)d_in[0];
  const float* key_feats = (const float*)d_in[1];
  const float* ref       = (const float*)d_in[2];
  const unsigned char* mask = (const unsigned char*)d_in[3];
  // d_in[4] = spatial_shapes (compile-time constants)
  const float* Wv    = (const float*)d_in[5];
  const float* bv    = (const float*)d_in[6];
  const float* Woff  = (const float*)d_in[7];
  const float* boff  = (const float*)d_in[8];
  const float* Wattn = (const float*)d_in[9];
  const float* battn = (const float*)d_in[10];
  const float* Wout  = (const float*)d_in[11];
  const float* bout  = (const float*)d_in[12];
  float* out = (float*)d_out;

  char* ws = (char*)d_ws;
  size_t off = 0;
  unsigned short* val   = (unsigned short*)(ws + off); off += (size_t)MVAL * 256 * 2;
  unsigned short* WT    = (unsigned short*)(ws + off); off += 256 * 256 * 2;
  unsigned short* WTq   = (unsigned short*)(ws + off); off += 768 * 256 * 2;
  unsigned short* WoutT = (unsigned short*)(ws + off); off += 256 * 256 * 2;
  unsigned short* qbf   = (unsigned short*)(ws + off); off += (size_t)NQ * 256 * 2;
  float* OFFLOG = (float*)(ws + off); off += (size_t)NQ * 768 * 4;
  unsigned short* slots = (unsigned short*)(ws + off); off += (size_t)NQ * 256 * 2;
  unsigned char* valid  = (unsigned char*)(ws + off); off += NCAMS * NQ;

  hipLaunchKernelGGL(k_prep, dim3(1280 + NQ), dim3(256), 0, stream,
                     Wv, Woff, Wattn, Wout, query, WT, WTq, WoutT, qbf);
  hipLaunchKernelGGL(k_abf, dim3(2048), dim3(256), 0, stream,
                     key_feats, val);   // bf16 A written into val buffer
  hipLaunchKernelGGL(k_valproj, dim3((MVAL + 127) / 128), dim3(512), 0, stream,
                     val, WT, bv, val); // in-place: row-disjoint per block
  hipLaunchKernelGGL(k_gemm_small, dim3((NQ + 127) / 128, 6), dim3(256), 0, stream,
                     qbf, WTq, boff, battn, 512, (const float*)nullptr, OFFLOG, NQ, 768, 0);
  hipLaunchKernelGGL(k_maskvalid, dim3((NCAMS * NQ + 255) / 256), dim3(256), 0, stream,
                     mask, valid);
  hipLaunchKernelGGL(k_sample, dim3(NQ), dim3(256), 0, stream,
                     val, OFFLOG, ref, valid, slots);
  hipLaunchKernelGGL(k_gemm_small, dim3((NQ + 127) / 128, 2), dim3(256), 0, stream,
                     slots, WoutT, bout, bout, 1 << 30, query, out, NQ, 256, 1);
}

// Round 11
// 166.565 us; speedup vs baseline: 2.4792x; 1.0135x over previous
//
#include <hip/hip_runtime.h>
#include <hip/hip_bf16.h>
#include <cstdint>

#define NCAMS 6
#define NQ 2500
#define EMBED 256
#define HEADS 8
#define DHEAD 32
#define LTOT 19560
#define MVAL (NCAMS * LTOT) /* 117360 */

typedef __attribute__((ext_vector_type(8))) short bf16x8;
typedef __attribute__((ext_vector_type(4))) float f32x4;

__device__ __forceinline__ unsigned short f2bf(float f) {
  unsigned u = __float_as_uint(f);
  return (unsigned short)((u + 0x7fffu + ((u >> 16) & 1u)) >> 16);
}
__device__ __forceinline__ unsigned short bfbits(float x) {
  __hip_bfloat16 h = __float2bfloat16(x);
  return __builtin_bit_cast(unsigned short, h);
}
__device__ __forceinline__ void gl16(const void* g, void* l) {
  __builtin_amdgcn_global_load_lds(
      (const __attribute__((address_space(1))) unsigned int*)g,
      (__attribute__((address_space(3))) unsigned int*)l, 16, 0, 0);
}

// ---------------------------------------------------------------------------
// Kernel P: weight transposes -> bf16, query -> bf16, AND bev_mask -> valid.
// grid 1280+NQ+59.
// ---------------------------------------------------------------------------
__global__ __launch_bounds__(256) void k_prep(
    const float* __restrict__ Wv, const float* __restrict__ Woff,
    const float* __restrict__ Wattn, const float* __restrict__ Wout,
    const float* __restrict__ query, const unsigned char* __restrict__ MSK,
    unsigned short* __restrict__ WT, unsigned short* __restrict__ WTq,
    unsigned short* __restrict__ WoutT, unsigned short* __restrict__ qbf,
    unsigned char* __restrict__ valid)
{
  const int b = blockIdx.x, t = threadIdx.x;
  if (b < 256) {
    WT[(size_t)b * 256 + t] = f2bf(Wv[(size_t)t * 256 + b]);
  } else if (b < 768) {
    int c = b - 256;
    WTq[(size_t)c * 256 + t] = f2bf(Woff[(size_t)t * 512 + c]);
  } else if (b < 1024) {
    int c = b - 768;
    WTq[(size_t)(512 + c) * 256 + t] = f2bf(Wattn[(size_t)t * 256 + c]);
  } else if (b < 1280) {
    int c = b - 1024;
    WoutT[(size_t)c * 256 + t] = f2bf(Wout[(size_t)t * 256 + c]);
  } else if (b < 1280 + NQ) {
    int q = b - 1280;
    qbf[(size_t)q * 256 + t] = f2bf(query[(size_t)q * 256 + t]);
  } else {
    // bev_mask -> valid, with on-device dtype detect (int32 vs u8 bools)
    __shared__ int s_u8;
    if (t == 0) s_u8 = 0;
    __syncthreads();
    if ((t & 3) && MSK[t]) atomicOr(&s_u8, 1);
    __syncthreads();
    const int isU8 = s_u8;
    const int i = (b - 1280 - NQ) * 256 + t;
    if (i < NCAMS * NQ) {
      int any;
      if (isU8) {
        const unsigned char* p = MSK + (size_t)i * 4;
        any = p[0] | p[1] | p[2] | p[3];
      } else {
        const int* p = (const int*)MSK + (size_t)i * 4;
        any = p[0] | p[1] | p[2] | p[3];
      }
      valid[i] = any ? 1 : 0;
    }
  }
}

// ---------------------------------------------------------------------------
// Kernel A (v7, fused convert+GEMM): val = bf16( A_f32 @ W_value + b_value )
// A staged as RAW F32 via global_load_lds width=16 (async); f32->bf16 at
// fragment-read time (cvt_pk fused by compiler). Pre-swizzled global source:
// A granule(16B) g' slot holds source granule g'^((row&7)<<1)  => fragment
// 32B unit u read at slot u^(row&7) (contiguous, 2-way bank = free).
// B bf16 staged as before (chunk ^ row&7). LDS 64KB -> 2 blocks/CU.
// Epilogue: per-wave LDS transpose -> 128B-contiguous stores (r10-proven).
// launch_bounds(512,4): VGPR cap 128 (est. need ~120).  (512,6)=spill (r7).
// ---------------------------------------------------------------------------
__global__ __launch_bounds__(512, 4) void k_valproj(
    const float* __restrict__ A,            // (117360, 256) f32
    const unsigned short* __restrict__ WT,  // (256 cols, 256 k) bf16
    const float* __restrict__ bv,           // (256,)
    unsigned short* __restrict__ val)       // (117360, 256) bf16
{
  __shared__ unsigned int smemu[16384];               // 64 KB
  float* Af = (float*)smemu;                          // [128][64] f32 (swizzled)
  unsigned short* Bs = (unsigned short*)(smemu + 8192); // [256][64] bf16 (swizzled)
  const int t = threadIdx.x;
  const int lane = t & 63;
  const int wid = t >> 6;
  const int wm = wid >> 2, wn = wid & 3;
  const int laneM = lane & 15, kGrp = lane >> 4;
  const int bm = blockIdx.x * 128;

  // ---- A staging sources: instr p covers lds 16B-granules (wid*4+p)*64+lane
  const float* aS[4];
#pragma unroll
  for (int p = 0; p < 4; ++p) {
    int g16 = (wid * 4 + p) * 64 + lane;
    int row = g16 >> 4;                 // 0..127
    int gl  = g16 & 15;
    int g   = gl ^ ((row & 7) << 1);    // pre-swizzled source granule
    aS[p] = A + (size_t)min(bm + row, MVAL - 1) * 256 + g * 4;
  }
  // ---- B staging sources (as r10: row p*64+sub, chunk swz) ----
  const int sub = t >> 3;
  const int swz = (t & 7) ^ (sub & 7);
  const unsigned short* bS[4];
#pragma unroll
  for (int p = 0; p < 4; ++p)
    bS[p] = WT + (size_t)(p * 64 + sub) * 256 + swz * 8;

  f32x4 acc[4][4];
#pragma unroll
  for (int m = 0; m < 4; ++m)
#pragma unroll
    for (int n = 0; n < 4; ++n) acc[m][n] = {0.f, 0.f, 0.f, 0.f};

#pragma unroll 1
  for (int kk = 0; kk < 4; ++kk) {
    if (kk) __syncthreads();   // previous compute done reading LDS
    const int koF = kk * 64;   // f32 elements
#pragma unroll
    for (int p = 0; p < 4; ++p)
      gl16(aS[p] + koF, Af + (wid * 4 + p) * 256);
#pragma unroll
    for (int p = 0; p < 4; ++p)
      gl16(bS[p] + koF, Bs + p * 4096 + wid * 512);
    __syncthreads();           // drains vmcnt -> staged data visible

#pragma unroll
    for (int ks = 0; ks < 2; ++ks) {
      bf16x8 af[4], bfr[4];
#pragma unroll
      for (int m = 0; m < 4; ++m) {
        int row = wm * 64 + m * 16 + laneM;
        int u = (ks * 4 + kGrp) ^ (row & 7);     // swizzled 32B-unit slot
        const float* p8 = &Af[row * 64 + u * 8];
        float4 x = *(const float4*)p8;
        float4 y = *(const float4*)(p8 + 4);
        union { bf16x8 v; unsigned short u16[8]; } c;
        c.u16[0] = bfbits(x.x); c.u16[1] = bfbits(x.y);
        c.u16[2] = bfbits(x.z); c.u16[3] = bfbits(x.w);
        c.u16[4] = bfbits(y.x); c.u16[5] = bfbits(y.y);
        c.u16[6] = bfbits(y.z); c.u16[7] = bfbits(y.w);
        af[m] = c.v;
      }
#pragma unroll
      for (int n = 0; n < 4; ++n) {
        int row = wn * 64 + n * 16 + laneM;
        bfr[n] = *(bf16x8*)&Bs[row * 64 + (((ks * 4 + kGrp) ^ (row & 7)) << 3)];
      }
#pragma unroll
      for (int m = 0; m < 4; ++m)
#pragma unroll
        for (int n = 0; n < 4; ++n)
          acc[m][n] = __builtin_amdgcn_mfma_f32_16x16x32_bf16(bfr[n], af[m], acc[m][n], 0, 0, 0);
    }
  }

  // ---- epilogue: swapped C/D (lane = row laneM, cols kGrp*4+r) ->
  // per-wave LDS transpose (reuses staging smem) -> 128B contiguous stores.
  float4 bb4[4];
#pragma unroll
  for (int n = 0; n < 4; ++n)
    bb4[n] = *(const float4*)&bv[wn * 64 + n * 16 + kGrp * 4];

  __syncthreads();  // all waves done reading Af/Bs
  unsigned short* tlw = (unsigned short*)smemu + wid * (32 * 72);

#pragma unroll
  for (int hm = 0; hm < 2; ++hm) {
#pragma unroll
    for (int mm = 0; mm < 2; ++mm) {
      const int m = hm * 2 + mm;
#pragma unroll
      for (int n = 0; n < 4; ++n) {
        uint2 u;
        u.x = (unsigned)bfbits(acc[m][n][0] + bb4[n].x) |
              ((unsigned)bfbits(acc[m][n][1] + bb4[n].y) << 16);
        u.y = (unsigned)bfbits(acc[m][n][2] + bb4[n].z) |
              ((unsigned)bfbits(acc[m][n][3] + bb4[n].w) << 16);
        *(uint2*)&tlw[(mm * 16 + laneM) * 72 + n * 16 + kGrp * 4] = u;
      }
    }
#pragma unroll
    for (int i = 0; i < 4; ++i) {
      const int rowl = i * 8 + (lane >> 3);
      const int c8 = lane & 7;
      uint4 v = *(const uint4*)&tlw[rowl * 72 + c8 * 8];
      const int row = bm + wm * 64 + hm * 32 + rowl;
      if (row < MVAL)
        *(uint4*)&val[(size_t)row * 256 + wn * 64 + c8 * 8] = v;
    }
  }
}

// ---------------------------------------------------------------------------
// Kernel G: generic small-M GEMM.  C(M,N) = A_bf16(M,256) @ BT_bf16(N,256)^T
//           + bias (split ba/bb at bsplit) [+ resid(M,256) if withResid]
// ---------------------------------------------------------------------------
__global__ __launch_bounds__(256, 2) void k_gemm_small(
    const unsigned short* __restrict__ A,
    const unsigned short* __restrict__ BT,
    const float* __restrict__ ba, const float* __restrict__ bb, int bsplit,
    const float* __restrict__ resid,
    float* __restrict__ C, int M, int N, int withResid)
{
  __shared__ unsigned short As[128 * 64];
  __shared__ unsigned short Bs[128 * 64];
  const int t = threadIdx.x;
  const int lane = t & 63;
  const int wid = t >> 6;
  const int wm = wid >> 1, wn = wid & 1;
  const int laneM = lane & 15, kGrp = lane >> 4;
  const int bm = blockIdx.x * 128;
  const int bn = blockIdx.y * 128;

  const int aC = t & 7, aR0 = t >> 3;

  uint4 aRegs[2][4];
  uint4 bRegs[2][4];
  f32x4 acc[4][4];
#pragma unroll
  for (int m = 0; m < 4; ++m)
#pragma unroll
    for (int n = 0; n < 4; ++n) acc[m][n] = {0.f, 0.f, 0.f, 0.f};

#pragma unroll
  for (int p = 0; p < 4; ++p) {
    int arow = bm + aR0 + p * 32;
    aRegs[0][p] = (arow < M) ? *(const uint4*)&A[(size_t)arow * 256 + aC * 8]
                             : make_uint4(0u, 0u, 0u, 0u);
    bRegs[0][p] = *(const uint4*)&BT[(size_t)(bn + aR0 + p * 32) * 256 + aC * 8];
  }

#pragma unroll
  for (int kk = 0; kk < 4; ++kk) {
    const int cur = kk & 1, nxt = cur ^ 1;
    if (kk) __syncthreads();
#pragma unroll
    for (int p = 0; p < 4; ++p) {
      int row = aR0 + p * 32;
      int elem = row * 64 + ((aC ^ (row & 7)) << 3);
      *(uint4*)&As[elem] = aRegs[cur][p];
      *(uint4*)&Bs[elem] = bRegs[cur][p];
    }
    __syncthreads();
    if (kk < 3) {
      const int kn = (kk + 1) * 64;
#pragma unroll
      for (int p = 0; p < 4; ++p) {
        int arow = bm + aR0 + p * 32;
        aRegs[nxt][p] = (arow < M)
            ? *(const uint4*)&A[(size_t)arow * 256 + kn + aC * 8]
            : make_uint4(0u, 0u, 0u, 0u);
        bRegs[nxt][p] = *(const uint4*)&BT[(size_t)(bn + aR0 + p * 32) * 256 + kn + aC * 8];
      }
    }
#pragma unroll
    for (int ks = 0; ks < 2; ++ks) {
      bf16x8 af[4], bfr[4];
#pragma unroll
      for (int m = 0; m < 4; ++m) {
        int row = wm * 64 + m * 16 + laneM;
        af[m] = *(bf16x8*)&As[row * 64 + (((ks * 4 + kGrp) ^ (row & 7)) << 3)];
      }
#pragma unroll
      for (int n = 0; n < 4; ++n) {
        int row = wn * 64 + n * 16 + laneM;
        bfr[n] = *(bf16x8*)&Bs[row * 64 + (((ks * 4 + kGrp) ^ (row & 7)) << 3)];
      }
#pragma unroll
      for (int m = 0; m < 4; ++m)
#pragma unroll
        for (int n = 0; n < 4; ++n)
          acc[m][n] = __builtin_amdgcn_mfma_f32_16x16x32_bf16(af[m], bfr[n], acc[m][n], 0, 0, 0);
    }
  }

  float bvn[4];
#pragma unroll
  for (int n = 0; n < 4; ++n) {
    int col = bn + wn * 64 + n * 16 + laneM;
    bvn[n] = (col < bsplit) ? ba[col] : bb[col - bsplit];
  }
#pragma unroll
  for (int m = 0; m < 4; ++m) {
#pragma unroll
    for (int r = 0; r < 4; ++r) {
      int row = bm + wm * 64 + m * 16 + kGrp * 4 + r;
      if (row < M) {
#pragma unroll
        for (int n = 0; n < 4; ++n) {
          int col = bn + wn * 64 + n * 16 + laneM;
          float v = acc[m][n][r] + bvn[n];
          if (withResid) v += resid[(size_t)row * 256 + col];
          C[(size_t)row * N + col] = v;
        }
      }
    }
  }
}

// ---------------------------------------------------------------------------
// Kernel C (two-phase sampling).  OFFLOG row = [OFF(512) | LOG(256)].
// ---------------------------------------------------------------------------
__global__ __launch_bounds__(256) void k_sample(
    const unsigned short* __restrict__ val,   // (117360, 256) bf16
    const float* __restrict__ OFFLOG,         // (2500, 768)
    const float* __restrict__ REF,            // (6,1,2500,4,2)
    const unsigned char* __restrict__ valid,  // (6,2500)
    unsigned short* __restrict__ slots)       // (2500,256) bf16
{
  __shared__ int2  s_pack[4][NCAMS][256];
  __shared__ float s_off[512];
  __shared__ float s_ref[48];
  __shared__ int   s_valid[6];

  const int q = blockIdx.x;
  const int t = threadIdx.x;

  s_off[t]       = OFFLOG[(size_t)q * 768 + t];
  s_off[t + 256] = OFFLOG[(size_t)q * 768 + 256 + t];
  if (t < 48) s_ref[t] = REF[(size_t)(t >> 3) * (NQ * 8) + (size_t)q * 8 + (t & 7)];
  if (t < 6) s_valid[t] = valid[(size_t)t * NQ + q];

  float logit = OFFLOG[(size_t)q * 768 + 512 + t];
  float m = logit;
#pragma unroll
  for (int o = 16; o > 0; o >>= 1) m = fmaxf(m, __shfl_xor(m, o, 32));
  float e = __expf(logit - m);
  float s = e;
#pragma unroll
  for (int o = 16; o > 0; o >>= 1) s += __shfl_xor(s, o, 32);
  const float a = e / s;
  __syncthreads();

  {
    const int h1 = t >> 5, lp = t & 31, lvl = lp >> 3, p = lp & 7, z = p & 3;
    const int WW = 160 >> lvl;
    const int HH = (lvl < 3) ? (92 >> lvl) : 12;
    const int S  = (lvl == 0) ? 0 : (lvl == 1) ? 14720 : (lvl == 2) ? 18400 : 19320;
    const float Wf = (float)WW, Hf = (float)HH;
    const float ox = s_off[h1 * 64 + lp * 2];
    const float oy = s_off[h1 * 64 + lp * 2 + 1];
#pragma unroll 1
    for (int cam = 0; cam < NCAMS; ++cam) {
      if (!s_valid[cam]) continue;
      float rx = s_ref[cam * 8 + z * 2];
      float ry = s_ref[cam * 8 + z * 2 + 1];
      float x = rx * Wf + ox - 0.5f;
      float y = ry * Hf + oy - 0.5f;
      float x0f = floorf(x), y0f = floorf(y);
      float fx = x - x0f, fy = y - y0f;
      int x0 = (int)x0f, y0 = (int)y0f;
      int base = cam * LTOT + S;
#pragma unroll
      for (int dy = 0; dy < 2; ++dy) {
        int yi = y0 + dy;
        float wy = dy ? fy : 1.f - fy;
        int yc = min(max(yi, 0), HH - 1);
        bool vy = (yi >= 0) && (yi < HH);
#pragma unroll
        for (int dx = 0; dx < 2; ++dx) {
          int xi = x0 + dx;
          float wx = dx ? fx : 1.f - fx;
          int xc = min(max(xi, 0), WW - 1);
          bool vv = vy && (xi >= 0) && (xi < WW);
          float wgt = vv ? wx * wy * a : 0.f;
          int addr = (base + yc * WW + xc) * 512;
          s_pack[dy * 2 + dx][cam][t] = make_int2(addr, __float_as_int(wgt));
        }
      }
    }
  }
  __syncthreads();

  const int h = t >> 5, pp = (t >> 3) & 3, l8 = t & 7;
  const unsigned dconst = (unsigned)(h * 64 + l8 * 8);
  const char* vb = (const char*)val;
  int nvalid = s_valid[0] + s_valid[1] + s_valid[2] + s_valid[3] + s_valid[4] + s_valid[5];
  float inv = 1.f / fmaxf((float)nvalid, 1.f);

  f32x4 acc = {0.f, 0.f, 0.f, 0.f};
#pragma unroll 1
  for (int cam = 0; cam < NCAMS; ++cam) {
    if (!s_valid[cam]) continue;
#pragma unroll
    for (int it = 0; it < 8; ++it) {
      const int idx = h * 32 + pp + it * 4;
      int2 pk0 = s_pack[0][cam][idx];
      int2 pk1 = s_pack[1][cam][idx];
      int2 pk2 = s_pack[2][cam][idx];
      int2 pk3 = s_pack[3][cam][idx];
      uint2 v0 = *(const uint2*)(vb + (size_t)((unsigned)pk0.x + dconst));
      uint2 v1 = *(const uint2*)(vb + (size_t)((unsigned)pk1.x + dconst));
      uint2 v2 = *(const uint2*)(vb + (size_t)((unsigned)pk2.x + dconst));
      uint2 v3 = *(const uint2*)(vb + (size_t)((unsigned)pk3.x + dconst));
      float w0 = __int_as_float(pk0.y), w1 = __int_as_float(pk1.y);
      float w2 = __int_as_float(pk2.y), w3 = __int_as_float(pk3.y);
      acc[0] += w0 * __uint_as_float(v0.x << 16);
      acc[1] += w0 * __uint_as_float(v0.x & 0xffff0000u);
      acc[2] += w0 * __uint_as_float(v0.y << 16);
      acc[3] += w0 * __uint_as_float(v0.y & 0xffff0000u);
      acc[0] += w1 * __uint_as_float(v1.x << 16);
      acc[1] += w1 * __uint_as_float(v1.x & 0xffff0000u);
      acc[2] += w1 * __uint_as_float(v1.y << 16);
      acc[3] += w1 * __uint_as_float(v1.y & 0xffff0000u);
      acc[0] += w2 * __uint_as_float(v2.x << 16);
      acc[1] += w2 * __uint_as_float(v2.x & 0xffff0000u);
      acc[2] += w2 * __uint_as_float(v2.y << 16);
      acc[3] += w2 * __uint_as_float(v2.y & 0xffff0000u);
      acc[0] += w3 * __uint_as_float(v3.x << 16);
      acc[1] += w3 * __uint_as_float(v3.x & 0xffff0000u);
      acc[2] += w3 * __uint_as_float(v3.y << 16);
      acc[3] += w3 * __uint_as_float(v3.y & 0xffff0000u);
    }
  }

#pragma unroll
  for (int i = 0; i < 4; ++i) {
    acc[i] += __shfl_xor(acc[i], 8);
    acc[i] += __shfl_xor(acc[i], 16);
  }
  if (pp == 0) {
    uint2 r;
    r.x = (unsigned)f2bf(acc[0] * inv) | ((unsigned)f2bf(acc[1] * inv) << 16);
    r.y = (unsigned)f2bf(acc[2] * inv) | ((unsigned)f2bf(acc[3] * inv) << 16);
    *(uint2*)&slots[(size_t)q * 256 + h * 32 + l8 * 4] = r;
  }
}

// ---------------------------------------------------------------------------
extern "C" void kernel_launch(void* const* d_in, const int* in_sizes, int n_in,
                              void* d_out, int out_size, void* d_ws, size_t ws_size,
                              hipStream_t stream) {
  const float* query     = (const float*)d_in[0];
  const float* key_feats = (const float*)d_in[1];
  const float* ref       = (const float*)d_in[2];
  const unsigned char* mask = (const unsigned char*)d_in[3];
  // d_in[4] = spatial_shapes (compile-time constants)
  const float* Wv    = (const float*)d_in[5];
  const float* bv    = (const float*)d_in[6];
  const float* Woff  = (const float*)d_in[7];
  const float* boff  = (const float*)d_in[8];
  const float* Wattn = (const float*)d_in[9];
  const float* battn = (const float*)d_in[10];
  const float* Wout  = (const float*)d_in[11];
  const float* bout  = (const float*)d_in[12];
  float* out = (float*)d_out;

  char* ws = (char*)d_ws;
  size_t off = 0;
  unsigned short* val   = (unsigned short*)(ws + off); off += (size_t)MVAL * 256 * 2;
  unsigned short* WT    = (unsigned short*)(ws + off); off += 256 * 256 * 2;
  unsigned short* WTq   = (unsigned short*)(ws + off); off += 768 * 256 * 2;
  unsigned short* WoutT = (unsigned short*)(ws + off); off += 256 * 256 * 2;
  unsigned short* qbf   = (unsigned short*)(ws + off); off += (size_t)NQ * 256 * 2;
  float* OFFLOG = (float*)(ws + off); off += (size_t)NQ * 768 * 4;
  unsigned short* slots = (unsigned short*)(ws + off); off += (size_t)NQ * 256 * 2;
  unsigned char* valid  = (unsigned char*)(ws + off); off += NCAMS * NQ;

  const int MASKBLKS = (NCAMS * NQ + 255) / 256;  // 59
  hipLaunchKernelGGL(k_prep, dim3(1280 + NQ + MASKBLKS), dim3(256), 0, stream,
                     Wv, Woff, Wattn, Wout, query, mask, WT, WTq, WoutT, qbf, valid);
  hipLaunchKernelGGL(k_valproj, dim3((MVAL + 127) / 128), dim3(512), 0, stream,
                     key_feats, WT, bv, val);
  hipLaunchKernelGGL(k_gemm_small, dim3((NQ + 127) / 128, 6), dim3(256), 0, stream,
                     qbf, WTq, boff, battn, 512, (const float*)nullptr, OFFLOG, NQ, 768, 0);
  hipLaunchKernelGGL(k_sample, dim3(NQ), dim3(256), 0, stream,
                     val, OFFLOG, ref, valid, slots);
  hipLaunchKernelGGL(k_gemm_small, dim3((NQ + 127) / 128, 2), dim3(256), 0, stream,
                     slots, WoutT, bout, bout, 1 << 30, query, out, NQ, 256, 1);
}

// Round 12
// 146.590 us; speedup vs baseline: 2.8170x; 1.1363x over previous
//
#include <hip/hip_runtime.h>
#include <hip/hip_bf16.h>
#include <cstdint>

#define NCAMS 6
#define NQ 2500
#define EMBED 256
#define HEADS 8
#define DHEAD 32
#define LTOT 19560
#define MVAL (NCAMS * LTOT) /* 117360 */

typedef __attribute__((ext_vector_type(8))) short bf16x8;
typedef __attribute__((ext_vector_type(4))) float f32x4;

__device__ __forceinline__ unsigned short f2bf(float f) {
  unsigned u = __float_as_uint(f);
  return (unsigned short)((u + 0x7fffu + ((u >> 16) & 1u)) >> 16);
}
__device__ __forceinline__ unsigned short bfbits(float x) {
  __hip_bfloat16 h = __float2bfloat16(x);
  return __builtin_bit_cast(unsigned short, h);
}
__device__ __forceinline__ void gl16(const void* g, void* l) {
  __builtin_amdgcn_global_load_lds(
      (const __attribute__((address_space(1))) unsigned int*)g,
      (__attribute__((address_space(3))) unsigned int*)l, 16, 0, 0);
}

// ---------------------------------------------------------------------------
// Kernel P: weight transposes -> bf16, query -> bf16, AND bev_mask -> valid.
// ---------------------------------------------------------------------------
__global__ __launch_bounds__(256) void k_prep(
    const float* __restrict__ Wv, const float* __restrict__ Woff,
    const float* __restrict__ Wattn, const float* __restrict__ Wout,
    const float* __restrict__ query, const unsigned char* __restrict__ MSK,
    unsigned short* __restrict__ WT, unsigned short* __restrict__ WTq,
    unsigned short* __restrict__ WoutT, unsigned short* __restrict__ qbf,
    unsigned char* __restrict__ valid)
{
  const int b = blockIdx.x, t = threadIdx.x;
  if (b < 256) {
    WT[(size_t)b * 256 + t] = f2bf(Wv[(size_t)t * 256 + b]);
  } else if (b < 768) {
    int c = b - 256;
    WTq[(size_t)c * 256 + t] = f2bf(Woff[(size_t)t * 512 + c]);
  } else if (b < 1024) {
    int c = b - 768;
    WTq[(size_t)(512 + c) * 256 + t] = f2bf(Wattn[(size_t)t * 256 + c]);
  } else if (b < 1280) {
    int c = b - 1024;
    WoutT[(size_t)c * 256 + t] = f2bf(Wout[(size_t)t * 256 + c]);
  } else if (b < 1280 + NQ) {
    int q = b - 1280;
    qbf[(size_t)q * 256 + t] = f2bf(query[(size_t)q * 256 + t]);
  } else {
    __shared__ int s_u8;
    if (t == 0) s_u8 = 0;
    __syncthreads();
    if ((t & 3) && MSK[t]) atomicOr(&s_u8, 1);
    __syncthreads();
    const int isU8 = s_u8;
    const int i = (b - 1280 - NQ) * 256 + t;
    if (i < NCAMS * NQ) {
      int any;
      if (isU8) {
        const unsigned char* p = MSK + (size_t)i * 4;
        any = p[0] | p[1] | p[2] | p[3];
      } else {
        const int* p = (const int*)MSK + (size_t)i * 4;
        any = p[0] | p[1] | p[2] | p[3];
      }
      valid[i] = any ? 1 : 0;
    }
  }
}

// ---------------------------------------------------------------------------
// Kernel A (v8): val = bf16( A_f32 @ W_value + b_value )
// Same as v7 (fused convert+GEMM, global_load_lds width=16) but A's swizzle
// is 16B-GRANULE level using 4 row bits: g = gl ^ ((row&7)<<1 | row_bit3).
// Each ds_read_b128 now spreads 64 lanes over all 8 bank groups (was even-
// only -> 8-way conflict, 1.9e7 cycles in r11). Read side swaps x/y halves
// when row bit3 is set (slot 2u+b3 holds source granule 2k).
// launch_bounds(512,4) = VGPR cap 128 (measured use 64).  (512,6)=spill.
// ---------------------------------------------------------------------------
__global__ __launch_bounds__(512, 4) void k_valproj(
    const float* __restrict__ A,            // (117360, 256) f32
    const unsigned short* __restrict__ WT,  // (256 cols, 256 k) bf16
    const float* __restrict__ bv,           // (256,)
    unsigned short* __restrict__ val)       // (117360, 256) bf16
{
  __shared__ unsigned int smemu[16384];               // 64 KB
  float* Af = (float*)smemu;                          // [128][64] f32 (swizzled)
  unsigned short* Bs = (unsigned short*)(smemu + 8192); // [256][64] bf16 (swizzled)
  const int t = threadIdx.x;
  const int lane = t & 63;
  const int wid = t >> 6;
  const int wm = wid >> 2, wn = wid & 3;
  const int laneM = lane & 15, kGrp = lane >> 4;
  const int b3 = (laneM >> 3) & 1;    // fragment-row bit3
  const int bm = blockIdx.x * 128;

  // ---- A staging sources: instr p covers lds 16B-granules (wid*4+p)*64+lane
  const float* aS[4];
#pragma unroll
  for (int p = 0; p < 4; ++p) {
    int g16 = (wid * 4 + p) * 64 + lane;
    int row = g16 >> 4;                 // 0..127
    int gl  = g16 & 15;
    int g   = gl ^ (((row & 7) << 1) | ((row >> 3) & 1)); // 4-bit granule swizzle
    aS[p] = A + (size_t)min(bm + row, MVAL - 1) * 256 + g * 4;
  }
  // ---- B staging sources (bf16, chunk ^ row&7) ----
  const int sub = t >> 3;
  const int swz = (t & 7) ^ (sub & 7);
  const unsigned short* bS[4];
#pragma unroll
  for (int p = 0; p < 4; ++p)
    bS[p] = WT + (size_t)(p * 64 + sub) * 256 + swz * 8;

  f32x4 acc[4][4];
#pragma unroll
  for (int m = 0; m < 4; ++m)
#pragma unroll
    for (int n = 0; n < 4; ++n) acc[m][n] = {0.f, 0.f, 0.f, 0.f};

#pragma unroll 1
  for (int kk = 0; kk < 4; ++kk) {
    if (kk) __syncthreads();
    const int koF = kk * 64;
#pragma unroll
    for (int p = 0; p < 4; ++p)
      gl16(aS[p] + koF, Af + (wid * 4 + p) * 256);
#pragma unroll
    for (int p = 0; p < 4; ++p)
      gl16(bS[p] + koF, Bs + p * 4096 + wid * 512);
    __syncthreads();

#pragma unroll
    for (int ks = 0; ks < 2; ++ks) {
      bf16x8 af[4], bfr[4];
#pragma unroll
      for (int m = 0; m < 4; ++m) {
        int row = wm * 64 + m * 16 + laneM;
        int u = (ks * 4 + kGrp) ^ (row & 7);
        const float* p8 = &Af[row * 64 + u * 8];
        float4 x = *(const float4*)(p8 + b3 * 4);        // slot 2u+b3 = src 2k
        float4 y = *(const float4*)(p8 + 4 - b3 * 4);    // slot 2u+1-b3 = src 2k+1
        union { bf16x8 v; unsigned short u16[8]; } c;
        c.u16[0] = bfbits(x.x); c.u16[1] = bfbits(x.y);
        c.u16[2] = bfbits(x.z); c.u16[3] = bfbits(x.w);
        c.u16[4] = bfbits(y.x); c.u16[5] = bfbits(y.y);
        c.u16[6] = bfbits(y.z); c.u16[7] = bfbits(y.w);
        af[m] = c.v;
      }
#pragma unroll
      for (int n = 0; n < 4; ++n) {
        int row = wn * 64 + n * 16 + laneM;
        bfr[n] = *(bf16x8*)&Bs[row * 64 + (((ks * 4 + kGrp) ^ (row & 7)) << 3)];
      }
#pragma unroll
      for (int m = 0; m < 4; ++m)
#pragma unroll
        for (int n = 0; n < 4; ++n)
          acc[m][n] = __builtin_amdgcn_mfma_f32_16x16x32_bf16(bfr[n], af[m], acc[m][n], 0, 0, 0);
    }
  }

  // ---- epilogue: per-wave LDS transpose -> 128B contiguous stores ----
  float4 bb4[4];
#pragma unroll
  for (int n = 0; n < 4; ++n)
    bb4[n] = *(const float4*)&bv[wn * 64 + n * 16 + kGrp * 4];

  __syncthreads();
  unsigned short* tlw = (unsigned short*)smemu + wid * (32 * 72);

#pragma unroll
  for (int hm = 0; hm < 2; ++hm) {
#pragma unroll
    for (int mm = 0; mm < 2; ++mm) {
      const int m = hm * 2 + mm;
#pragma unroll
      for (int n = 0; n < 4; ++n) {
        uint2 u;
        u.x = (unsigned)bfbits(acc[m][n][0] + bb4[n].x) |
              ((unsigned)bfbits(acc[m][n][1] + bb4[n].y) << 16);
        u.y = (unsigned)bfbits(acc[m][n][2] + bb4[n].z) |
              ((unsigned)bfbits(acc[m][n][3] + bb4[n].w) << 16);
        *(uint2*)&tlw[(mm * 16 + laneM) * 72 + n * 16 + kGrp * 4] = u;
      }
    }
#pragma unroll
    for (int i = 0; i < 4; ++i) {
      const int rowl = i * 8 + (lane >> 3);
      const int c8 = lane & 7;
      uint4 v = *(const uint4*)&tlw[rowl * 72 + c8 * 8];
      const int row = bm + wm * 64 + hm * 32 + rowl;
      if (row < MVAL)
        *(uint4*)&val[(size_t)row * 256 + wn * 64 + c8 * 8] = v;
    }
  }
}

// ---------------------------------------------------------------------------
// Kernel G: generic small-M GEMM.  C(M,N) = A_bf16(M,256) @ BT_bf16(N,256)^T
// ---------------------------------------------------------------------------
__global__ __launch_bounds__(256, 2) void k_gemm_small(
    const unsigned short* __restrict__ A,
    const unsigned short* __restrict__ BT,
    const float* __restrict__ ba, const float* __restrict__ bb, int bsplit,
    const float* __restrict__ resid,
    float* __restrict__ C, int M, int N, int withResid)
{
  __shared__ unsigned short As[128 * 64];
  __shared__ unsigned short Bs[128 * 64];
  const int t = threadIdx.x;
  const int lane = t & 63;
  const int wid = t >> 6;
  const int wm = wid >> 1, wn = wid & 1;
  const int laneM = lane & 15, kGrp = lane >> 4;
  const int bm = blockIdx.x * 128;
  const int bn = blockIdx.y * 128;

  const int aC = t & 7, aR0 = t >> 3;

  uint4 aRegs[2][4];
  uint4 bRegs[2][4];
  f32x4 acc[4][4];
#pragma unroll
  for (int m = 0; m < 4; ++m)
#pragma unroll
    for (int n = 0; n < 4; ++n) acc[m][n] = {0.f, 0.f, 0.f, 0.f};

#pragma unroll
  for (int p = 0; p < 4; ++p) {
    int arow = bm + aR0 + p * 32;
    aRegs[0][p] = (arow < M) ? *(const uint4*)&A[(size_t)arow * 256 + aC * 8]
                             : make_uint4(0u, 0u, 0u, 0u);
    bRegs[0][p] = *(const uint4*)&BT[(size_t)(bn + aR0 + p * 32) * 256 + aC * 8];
  }

#pragma unroll
  for (int kk = 0; kk < 4; ++kk) {
    const int cur = kk & 1, nxt = cur ^ 1;
    if (kk) __syncthreads();
#pragma unroll
    for (int p = 0; p < 4; ++p) {
      int row = aR0 + p * 32;
      int elem = row * 64 + ((aC ^ (row & 7)) << 3);
      *(uint4*)&As[elem] = aRegs[cur][p];
      *(uint4*)&Bs[elem] = bRegs[cur][p];
    }
    __syncthreads();
    if (kk < 3) {
      const int kn = (kk + 1) * 64;
#pragma unroll
      for (int p = 0; p < 4; ++p) {
        int arow = bm + aR0 + p * 32;
        aRegs[nxt][p] = (arow < M)
            ? *(const uint4*)&A[(size_t)arow * 256 + kn + aC * 8]
            : make_uint4(0u, 0u, 0u, 0u);
        bRegs[nxt][p] = *(const uint4*)&BT[(size_t)(bn + aR0 + p * 32) * 256 + kn + aC * 8];
      }
    }
#pragma unroll
    for (int ks = 0; ks < 2; ++ks) {
      bf16x8 af[4], bfr[4];
#pragma unroll
      for (int m = 0; m < 4; ++m) {
        int row = wm * 64 + m * 16 + laneM;
        af[m] = *(bf16x8*)&As[row * 64 + (((ks * 4 + kGrp) ^ (row & 7)) << 3)];
      }
#pragma unroll
      for (int n = 0; n < 4; ++n) {
        int row = wn * 64 + n * 16 + laneM;
        bfr[n] = *(bf16x8*)&Bs[row * 64 + (((ks * 4 + kGrp) ^ (row & 7)) << 3)];
      }
#pragma unroll
      for (int m = 0; m < 4; ++m)
#pragma unroll
        for (int n = 0; n < 4; ++n)
          acc[m][n] = __builtin_amdgcn_mfma_f32_16x16x32_bf16(af[m], bfr[n], acc[m][n], 0, 0, 0);
    }
  }

  float bvn[4];
#pragma unroll
  for (int n = 0; n < 4; ++n) {
    int col = bn + wn * 64 + n * 16 + laneM;
    bvn[n] = (col < bsplit) ? ba[col] : bb[col - bsplit];
  }
#pragma unroll
  for (int m = 0; m < 4; ++m) {
#pragma unroll
    for (int r = 0; r < 4; ++r) {
      int row = bm + wm * 64 + m * 16 + kGrp * 4 + r;
      if (row < M) {
#pragma unroll
        for (int n = 0; n < 4; ++n) {
          int col = bn + wn * 64 + n * 16 + laneM;
          float v = acc[m][n][r] + bvn[n];
          if (withResid) v += resid[(size_t)row * 256 + col];
          C[(size_t)row * N + col] = v;
        }
      }
    }
  }
}

// ---------------------------------------------------------------------------
// Kernel C (two-phase sampling).  OFFLOG row = [OFF(512) | LOG(256)].
// ---------------------------------------------------------------------------
__global__ __launch_bounds__(256) void k_sample(
    const unsigned short* __restrict__ val,   // (117360, 256) bf16
    const float* __restrict__ OFFLOG,         // (2500, 768)
    const float* __restrict__ REF,            // (6,1,2500,4,2)
    const unsigned char* __restrict__ valid,  // (6,2500)
    unsigned short* __restrict__ slots)       // (2500,256) bf16
{
  __shared__ int2  s_pack[4][NCAMS][256];
  __shared__ float s_off[512];
  __shared__ float s_ref[48];
  __shared__ int   s_valid[6];

  const int q = blockIdx.x;
  const int t = threadIdx.x;

  s_off[t]       = OFFLOG[(size_t)q * 768 + t];
  s_off[t + 256] = OFFLOG[(size_t)q * 768 + 256 + t];
  if (t < 48) s_ref[t] = REF[(size_t)(t >> 3) * (NQ * 8) + (size_t)q * 8 + (t & 7)];
  if (t < 6) s_valid[t] = valid[(size_t)t * NQ + q];

  float logit = OFFLOG[(size_t)q * 768 + 512 + t];
  float m = logit;
#pragma unroll
  for (int o = 16; o > 0; o >>= 1) m = fmaxf(m, __shfl_xor(m, o, 32));
  float e = __expf(logit - m);
  float s = e;
#pragma unroll
  for (int o = 16; o > 0; o >>= 1) s += __shfl_xor(s, o, 32);
  const float a = e / s;
  __syncthreads();

  {
    const int h1 = t >> 5, lp = t & 31, lvl = lp >> 3, p = lp & 7, z = p & 3;
    const int WW = 160 >> lvl;
    const int HH = (lvl < 3) ? (92 >> lvl) : 12;
    const int S  = (lvl == 0) ? 0 : (lvl == 1) ? 14720 : (lvl == 2) ? 18400 : 19320;
    const float Wf = (float)WW, Hf = (float)HH;
    const float ox = s_off[h1 * 64 + lp * 2];
    const float oy = s_off[h1 * 64 + lp * 2 + 1];
#pragma unroll 1
    for (int cam = 0; cam < NCAMS; ++cam) {
      if (!s_valid[cam]) continue;
      float rx = s_ref[cam * 8 + z * 2];
      float ry = s_ref[cam * 8 + z * 2 + 1];
      float x = rx * Wf + ox - 0.5f;
      float y = ry * Hf + oy - 0.5f;
      float x0f = floorf(x), y0f = floorf(y);
      float fx = x - x0f, fy = y - y0f;
      int x0 = (int)x0f, y0 = (int)y0f;
      int base = cam * LTOT + S;
#pragma unroll
      for (int dy = 0; dy < 2; ++dy) {
        int yi = y0 + dy;
        float wy = dy ? fy : 1.f - fy;
        int yc = min(max(yi, 0), HH - 1);
        bool vy = (yi >= 0) && (yi < HH);
#pragma unroll
        for (int dx = 0; dx < 2; ++dx) {
          int xi = x0 + dx;
          float wx = dx ? fx : 1.f - fx;
          int xc = min(max(xi, 0), WW - 1);
          bool vv = vy && (xi >= 0) && (xi < WW);
          float wgt = vv ? wx * wy * a : 0.f;
          int addr = (base + yc * WW + xc) * 512;
          s_pack[dy * 2 + dx][cam][t] = make_int2(addr, __float_as_int(wgt));
        }
      }
    }
  }
  __syncthreads();

  const int h = t >> 5, pp = (t >> 3) & 3, l8 = t & 7;
  const unsigned dconst = (unsigned)(h * 64 + l8 * 8);
  const char* vb = (const char*)val;
  int nvalid = s_valid[0] + s_valid[1] + s_valid[2] + s_valid[3] + s_valid[4] + s_valid[5];
  float inv = 1.f / fmaxf((float)nvalid, 1.f);

  f32x4 acc = {0.f, 0.f, 0.f, 0.f};
#pragma unroll 1
  for (int cam = 0; cam < NCAMS; ++cam) {
    if (!s_valid[cam]) continue;
#pragma unroll
    for (int it = 0; it < 8; ++it) {
      const int idx = h * 32 + pp + it * 4;
      int2 pk0 = s_pack[0][cam][idx];
      int2 pk1 = s_pack[1][cam][idx];
      int2 pk2 = s_pack[2][cam][idx];
      int2 pk3 = s_pack[3][cam][idx];
      uint2 v0 = *(const uint2*)(vb + (size_t)((unsigned)pk0.x + dconst));
      uint2 v1 = *(const uint2*)(vb + (size_t)((unsigned)pk1.x + dconst));
      uint2 v2 = *(const uint2*)(vb + (size_t)((unsigned)pk2.x + dconst));
      uint2 v3 = *(const uint2*)(vb + (size_t)((unsigned)pk3.x + dconst));
      float w0 = __int_as_float(pk0.y), w1 = __int_as_float(pk1.y);
      float w2 = __int_as_float(pk2.y), w3 = __int_as_float(pk3.y);
      acc[0] += w0 * __uint_as_float(v0.x << 16);
      acc[1] += w0 * __uint_as_float(v0.x & 0xffff0000u);
      acc[2] += w0 * __uint_as_float(v0.y << 16);
      acc[3] += w0 * __uint_as_float(v0.y & 0xffff0000u);
      acc[0] += w1 * __uint_as_float(v1.x << 16);
      acc[1] += w1 * __uint_as_float(v1.x & 0xffff0000u);
      acc[2] += w1 * __uint_as_float(v1.y << 16);
      acc[3] += w1 * __uint_as_float(v1.y & 0xffff0000u);
      acc[0] += w2 * __uint_as_float(v2.x << 16);
      acc[1] += w2 * __uint_as_float(v2.x & 0xffff0000u);
      acc[2] += w2 * __uint_as_float(v2.y << 16);
      acc[3] += w2 * __uint_as_float(v2.y & 0xffff0000u);
      acc[0] += w3 * __uint_as_float(v3.x << 16);
      acc[1] += w3 * __uint_as_float(v3.x & 0xffff0000u);
      acc[2] += w3 * __uint_as_float(v3.y << 16);
      acc[3] += w3 * __uint_as_float(v3.y & 0xffff0000u);
    }
  }

#pragma unroll
  for (int i = 0; i < 4; ++i) {
    acc[i] += __shfl_xor(acc[i], 8);
    acc[i] += __shfl_xor(acc[i], 16);
  }
  if (pp == 0) {
    uint2 r;
    r.x = (unsigned)f2bf(acc[0] * inv) | ((unsigned)f2bf(acc[1] * inv) << 16);
    r.y = (unsigned)f2bf(acc[2] * inv) | ((unsigned)f2bf(acc[3] * inv) << 16);
    *(uint2*)&slots[(size_t)q * 256 + h * 32 + l8 * 4] = r;
  }
}

// ---------------------------------------------------------------------------
extern "C" void kernel_launch(void* const* d_in, const int* in_sizes, int n_in,
                              void* d_out, int out_size, void* d_ws, size_t ws_size,
                              hipStream_t stream) {
  const float* query     = (const float*)d_in[0];
  const float* key_feats = (const float*)d_in[1];
  const float* ref       = (const float*)d_in[2];
  const unsigned char* mask = (const unsigned char*)d_in[3];
  // d_in[4] = spatial_shapes (compile-time constants)
  const float* Wv    = (const float*)d_in[5];
  const float* bv    = (const float*)d_in[6];
  const float* Woff  = (const float*)d_in[7];
  const float* boff  = (const float*)d_in[8];
  const float* Wattn = (const float*)d_in[9];
  const float* battn = (const float*)d_in[10];
  const float* Wout  = (const float*)d_in[11];
  const float* bout  = (const float*)d_in[12];
  float* out = (float*)d_out;

  char* ws = (char*)d_ws;
  size_t off = 0;
  unsigned short* val   = (unsigned short*)(ws + off); off += (size_t)MVAL * 256 * 2;
  unsigned short* WT    = (unsigned short*)(ws + off); off += 256 * 256 * 2;
  unsigned short* WTq   = (unsigned short*)(ws + off); off += 768 * 256 * 2;
  unsigned short* WoutT = (unsigned short*)(ws + off); off += 256 * 256 * 2;
  unsigned short* qbf   = (unsigned short*)(ws + off); off += (size_t)NQ * 256 * 2;
  float* OFFLOG = (float*)(ws + off); off += (size_t)NQ * 768 * 4;
  unsigned short* slots = (unsigned short*)(ws + off); off += (size_t)NQ * 256 * 2;
  unsigned char* valid  = (unsigned char*)(ws + off); off += NCAMS * NQ;

  const int MASKBLKS = (NCAMS * NQ + 255) / 256;  // 59
  hipLaunchKernelGGL(k_prep, dim3(1280 + NQ + MASKBLKS), dim3(256), 0, stream,
                     Wv, Woff, Wattn, Wout, query, mask, WT, WTq, WoutT, qbf, valid);
  hipLaunchKernelGGL(k_valproj, dim3((MVAL + 127) / 128), dim3(512), 0, stream,
                     key_feats, WT, bv, val);
  hipLaunchKernelGGL(k_gemm_small, dim3((NQ + 127) / 128, 6), dim3(256), 0, stream,
                     qbf, WTq, boff, battn, 512, (const float*)nullptr, OFFLOG, NQ, 768, 0);
  hipLaunchKernelGGL(k_sample, dim3(NQ), dim3(256), 0, stream,
                     val, OFFLOG, ref, valid, slots);
  hipLaunchKernelGGL(k_gemm_small, dim3((NQ + 127) / 128, 2), dim3(256), 0, stream,
                     slots, WoutT, bout, bout, 1 << 30, query, out, NQ, 256, 1);
}

// Round 13
// 144.547 us; speedup vs baseline: 2.8568x; 1.0141x over previous
//
#include <hip/hip_runtime.h>
#include <hip/hip_bf16.h>
#include <cstdint>

#define NCAMS 6
#define NQ 2500
#define EMBED 256
#define HEADS 8
#define DHEAD 32
#define LTOT 19560
#define MVAL (NCAMS * LTOT) /* 117360 */

typedef __attribute__((ext_vector_type(8))) short bf16x8;
typedef __attribute__((ext_vector_type(4))) float f32x4;

__device__ __forceinline__ unsigned short f2bf(float f) {
  unsigned u = __float_as_uint(f);
  return (unsigned short)((u + 0x7fffu + ((u >> 16) & 1u)) >> 16);
}
__device__ __forceinline__ unsigned short bfbits(float x) {
  __hip_bfloat16 h = __float2bfloat16(x);
  return __builtin_bit_cast(unsigned short, h);
}
__device__ __forceinline__ void gl16(const void* g, void* l) {
  __builtin_amdgcn_global_load_lds(
      (const __attribute__((address_space(1))) unsigned int*)g,
      (__attribute__((address_space(3))) unsigned int*)l, 16, 0, 0);
}

// ---------------------------------------------------------------------------
// Kernel P: weight transposes -> bf16, query -> bf16, AND bev_mask -> valid.
// ---------------------------------------------------------------------------
__global__ __launch_bounds__(256) void k_prep(
    const float* __restrict__ Wv, const float* __restrict__ Woff,
    const float* __restrict__ Wattn, const float* __restrict__ Wout,
    const float* __restrict__ query, const unsigned char* __restrict__ MSK,
    unsigned short* __restrict__ WT, unsigned short* __restrict__ WTq,
    unsigned short* __restrict__ WoutT, unsigned short* __restrict__ qbf,
    unsigned char* __restrict__ valid)
{
  const int b = blockIdx.x, t = threadIdx.x;
  if (b < 256) {
    WT[(size_t)b * 256 + t] = f2bf(Wv[(size_t)t * 256 + b]);
  } else if (b < 768) {
    int c = b - 256;
    WTq[(size_t)c * 256 + t] = f2bf(Woff[(size_t)t * 512 + c]);
  } else if (b < 1024) {
    int c = b - 768;
    WTq[(size_t)(512 + c) * 256 + t] = f2bf(Wattn[(size_t)t * 256 + c]);
  } else if (b < 1280) {
    int c = b - 1024;
    WoutT[(size_t)c * 256 + t] = f2bf(Wout[(size_t)t * 256 + c]);
  } else if (b < 1280 + NQ) {
    int q = b - 1280;
    qbf[(size_t)q * 256 + t] = f2bf(query[(size_t)q * 256 + t]);
  } else {
    __shared__ int s_u8;
    if (t == 0) s_u8 = 0;
    __syncthreads();
    if ((t & 3) && MSK[t]) atomicOr(&s_u8, 1);
    __syncthreads();
    const int isU8 = s_u8;
    const int i = (b - 1280 - NQ) * 256 + t;
    if (i < NCAMS * NQ) {
      int any;
      if (isU8) {
        const unsigned char* p = MSK + (size_t)i * 4;
        any = p[0] | p[1] | p[2] | p[3];
      } else {
        const int* p = (const int*)MSK + (size_t)i * 4;
        any = p[0] | p[1] | p[2] | p[3];
      }
      valid[i] = any ? 1 : 0;
    }
  }
}

// ---------------------------------------------------------------------------
// Kernel A (v9): val = bf16( A_f32 @ W_value + b_value )
// v8's fused convert+GEMM with BM 128->64: LDS 48KB (A f32 16K + B bf16 32K)
// -> 3 blocks/CU (was 2) for deeper cross-block latency hiding at the
// barrier drains. Wave tile 32x64, acc[2][4]. Same 4-bit granule swizzle
// (g = gl ^ ((row&7)<<1 | row_bit3), conflict-free per r12), swapped-operand
// MFMA, per-wave LDS-transpose epilogue with 128B-contiguous stores.
// launch_bounds MUST stay (512,4) — see r7 spill disaster at higher values.
// ---------------------------------------------------------------------------
__global__ __launch_bounds__(512, 4) void k_valproj(
    const float* __restrict__ A,            // (117360, 256) f32
    const unsigned short* __restrict__ WT,  // (256 cols, 256 k) bf16
    const float* __restrict__ bv,           // (256,)
    unsigned short* __restrict__ val)       // (117360, 256) bf16
{
  __shared__ unsigned int smemu[12288];                 // 48 KB
  float* Af = (float*)smemu;                            // [64][64] f32 (swizzled)
  unsigned short* Bs = (unsigned short*)(smemu + 4096); // [256][64] bf16 (swizzled)
  const int t = threadIdx.x;
  const int lane = t & 63;
  const int wid = t >> 6;
  const int wm = wid >> 2, wn = wid & 3;
  const int laneM = lane & 15, kGrp = lane >> 4;
  const int b3 = (laneM >> 3) & 1;    // fragment-row bit3
  const int bm = blockIdx.x * 64;

  // ---- A staging sources: instr p covers lds 16B-granules (wid*2+p)*64+lane
  const float* aS[2];
#pragma unroll
  for (int p = 0; p < 2; ++p) {
    int g16 = (wid * 2 + p) * 64 + lane;
    int row = g16 >> 4;                 // 0..63
    int gl  = g16 & 15;
    int g   = gl ^ (((row & 7) << 1) | ((row >> 3) & 1)); // 4-bit granule swizzle
    aS[p] = A + (size_t)min(bm + row, MVAL - 1) * 256 + g * 4;
  }
  // ---- B staging sources (bf16, chunk ^ row&7) ----
  const int sub = t >> 3;
  const int swz = (t & 7) ^ (sub & 7);
  const unsigned short* bS[4];
#pragma unroll
  for (int p = 0; p < 4; ++p)
    bS[p] = WT + (size_t)(p * 64 + sub) * 256 + swz * 8;

  f32x4 acc[2][4];
#pragma unroll
  for (int m = 0; m < 2; ++m)
#pragma unroll
    for (int n = 0; n < 4; ++n) acc[m][n] = {0.f, 0.f, 0.f, 0.f};

#pragma unroll 1
  for (int kk = 0; kk < 4; ++kk) {
    if (kk) __syncthreads();
    const int koF = kk * 64;
#pragma unroll
    for (int p = 0; p < 2; ++p)
      gl16(aS[p] + koF, Af + (wid * 2 + p) * 256);
#pragma unroll
    for (int p = 0; p < 4; ++p)
      gl16(bS[p] + koF, Bs + p * 4096 + wid * 512);
    __syncthreads();

#pragma unroll
    for (int ks = 0; ks < 2; ++ks) {
      bf16x8 af[2], bfr[4];
#pragma unroll
      for (int m = 0; m < 2; ++m) {
        int row = wm * 32 + m * 16 + laneM;
        int u = (ks * 4 + kGrp) ^ (row & 7);
        const float* p8 = &Af[row * 64 + u * 8];
        float4 x = *(const float4*)(p8 + b3 * 4);        // slot 2u+b3 = src 2k
        float4 y = *(const float4*)(p8 + 4 - b3 * 4);    // slot 2u+1-b3 = src 2k+1
        union { bf16x8 v; unsigned short u16[8]; } c;
        c.u16[0] = bfbits(x.x); c.u16[1] = bfbits(x.y);
        c.u16[2] = bfbits(x.z); c.u16[3] = bfbits(x.w);
        c.u16[4] = bfbits(y.x); c.u16[5] = bfbits(y.y);
        c.u16[6] = bfbits(y.z); c.u16[7] = bfbits(y.w);
        af[m] = c.v;
      }
#pragma unroll
      for (int n = 0; n < 4; ++n) {
        int row = wn * 64 + n * 16 + laneM;
        bfr[n] = *(bf16x8*)&Bs[row * 64 + (((ks * 4 + kGrp) ^ (row & 7)) << 3)];
      }
#pragma unroll
      for (int m = 0; m < 2; ++m)
#pragma unroll
        for (int n = 0; n < 4; ++n)
          acc[m][n] = __builtin_amdgcn_mfma_f32_16x16x32_bf16(bfr[n], af[m], acc[m][n], 0, 0, 0);
    }
  }

  // ---- epilogue: per-wave LDS transpose -> 128B contiguous stores ----
  float4 bb4[4];
#pragma unroll
  for (int n = 0; n < 4; ++n)
    bb4[n] = *(const float4*)&bv[wn * 64 + n * 16 + kGrp * 4];

  __syncthreads();
  unsigned short* tlw = (unsigned short*)smemu + wid * (32 * 72);

#pragma unroll
  for (int m = 0; m < 2; ++m) {
#pragma unroll
    for (int n = 0; n < 4; ++n) {
      uint2 u;
      u.x = (unsigned)bfbits(acc[m][n][0] + bb4[n].x) |
            ((unsigned)bfbits(acc[m][n][1] + bb4[n].y) << 16);
      u.y = (unsigned)bfbits(acc[m][n][2] + bb4[n].z) |
            ((unsigned)bfbits(acc[m][n][3] + bb4[n].w) << 16);
      *(uint2*)&tlw[(m * 16 + laneM) * 72 + n * 16 + kGrp * 4] = u;
    }
  }
#pragma unroll
  for (int i = 0; i < 4; ++i) {
    const int rowl = i * 8 + (lane >> 3);
    const int c8 = lane & 7;
    uint4 v = *(const uint4*)&tlw[rowl * 72 + c8 * 8];
    const int row = bm + wm * 32 + rowl;
    if (row < MVAL)
      *(uint4*)&val[(size_t)row * 256 + wn * 64 + c8 * 8] = v;
  }
}

// ---------------------------------------------------------------------------
// Kernel G: generic small-M GEMM.  C(M,N) = A_bf16(M,256) @ BT_bf16(N,256)^T
// ---------------------------------------------------------------------------
__global__ __launch_bounds__(256, 2) void k_gemm_small(
    const unsigned short* __restrict__ A,
    const unsigned short* __restrict__ BT,
    const float* __restrict__ ba, const float* __restrict__ bb, int bsplit,
    const float* __restrict__ resid,
    float* __restrict__ C, int M, int N, int withResid)
{
  __shared__ unsigned short As[128 * 64];
  __shared__ unsigned short Bs[128 * 64];
  const int t = threadIdx.x;
  const int lane = t & 63;
  const int wid = t >> 6;
  const int wm = wid >> 1, wn = wid & 1;
  const int laneM = lane & 15, kGrp = lane >> 4;
  const int bm = blockIdx.x * 128;
  const int bn = blockIdx.y * 128;

  const int aC = t & 7, aR0 = t >> 3;

  uint4 aRegs[2][4];
  uint4 bRegs[2][4];
  f32x4 acc[4][4];
#pragma unroll
  for (int m = 0; m < 4; ++m)
#pragma unroll
    for (int n = 0; n < 4; ++n) acc[m][n] = {0.f, 0.f, 0.f, 0.f};

#pragma unroll
  for (int p = 0; p < 4; ++p) {
    int arow = bm + aR0 + p * 32;
    aRegs[0][p] = (arow < M) ? *(const uint4*)&A[(size_t)arow * 256 + aC * 8]
                             : make_uint4(0u, 0u, 0u, 0u);
    bRegs[0][p] = *(const uint4*)&BT[(size_t)(bn + aR0 + p * 32) * 256 + aC * 8];
  }

#pragma unroll
  for (int kk = 0; kk < 4; ++kk) {
    const int cur = kk & 1, nxt = cur ^ 1;
    if (kk) __syncthreads();
#pragma unroll
    for (int p = 0; p < 4; ++p) {
      int row = aR0 + p * 32;
      int elem = row * 64 + ((aC ^ (row & 7)) << 3);
      *(uint4*)&As[elem] = aRegs[cur][p];
      *(uint4*)&Bs[elem] = bRegs[cur][p];
    }
    __syncthreads();
    if (kk < 3) {
      const int kn = (kk + 1) * 64;
#pragma unroll
      for (int p = 0; p < 4; ++p) {
        int arow = bm + aR0 + p * 32;
        aRegs[nxt][p] = (arow < M)
            ? *(const uint4*)&A[(size_t)arow * 256 + kn + aC * 8]
            : make_uint4(0u, 0u, 0u, 0u);
        bRegs[nxt][p] = *(const uint4*)&BT[(size_t)(bn + aR0 + p * 32) * 256 + kn + aC * 8];
      }
    }
#pragma unroll
    for (int ks = 0; ks < 2; ++ks) {
      bf16x8 af[4], bfr[4];
#pragma unroll
      for (int m = 0; m < 4; ++m) {
        int row = wm * 64 + m * 16 + laneM;
        af[m] = *(bf16x8*)&As[row * 64 + (((ks * 4 + kGrp) ^ (row & 7)) << 3)];
      }
#pragma unroll
      for (int n = 0; n < 4; ++n) {
        int row = wn * 64 + n * 16 + laneM;
        bfr[n] = *(bf16x8*)&Bs[row * 64 + (((ks * 4 + kGrp) ^ (row & 7)) << 3)];
      }
#pragma unroll
      for (int m = 0; m < 4; ++m)
#pragma unroll
        for (int n = 0; n < 4; ++n)
          acc[m][n] = __builtin_amdgcn_mfma_f32_16x16x32_bf16(af[m], bfr[n], acc[m][n], 0, 0, 0);
    }
  }

  float bvn[4];
#pragma unroll
  for (int n = 0; n < 4; ++n) {
    int col = bn + wn * 64 + n * 16 + laneM;
    bvn[n] = (col < bsplit) ? ba[col] : bb[col - bsplit];
  }
#pragma unroll
  for (int m = 0; m < 4; ++m) {
#pragma unroll
    for (int r = 0; r < 4; ++r) {
      int row = bm + wm * 64 + m * 16 + kGrp * 4 + r;
      if (row < M) {
#pragma unroll
        for (int n = 0; n < 4; ++n) {
          int col = bn + wn * 64 + n * 16 + laneM;
          float v = acc[m][n][r] + bvn[n];
          if (withResid) v += resid[(size_t)row * 256 + col];
          C[(size_t)row * N + col] = v;
        }
      }
    }
  }
}

// ---------------------------------------------------------------------------
// Kernel C (two-phase sampling).  OFFLOG row = [OFF(512) | LOG(256)].
// ---------------------------------------------------------------------------
__global__ __launch_bounds__(256) void k_sample(
    const unsigned short* __restrict__ val,   // (117360, 256) bf16
    const float* __restrict__ OFFLOG,         // (2500, 768)
    const float* __restrict__ REF,            // (6,1,2500,4,2)
    const unsigned char* __restrict__ valid,  // (6,2500)
    unsigned short* __restrict__ slots)       // (2500,256) bf16
{
  __shared__ int2  s_pack[4][NCAMS][256];
  __shared__ float s_off[512];
  __shared__ float s_ref[48];
  __shared__ int   s_valid[6];

  const int q = blockIdx.x;
  const int t = threadIdx.x;

  s_off[t]       = OFFLOG[(size_t)q * 768 + t];
  s_off[t + 256] = OFFLOG[(size_t)q * 768 + 256 + t];
  if (t < 48) s_ref[t] = REF[(size_t)(t >> 3) * (NQ * 8) + (size_t)q * 8 + (t & 7)];
  if (t < 6) s_valid[t] = valid[(size_t)t * NQ + q];

  float logit = OFFLOG[(size_t)q * 768 + 512 + t];
  float m = logit;
#pragma unroll
  for (int o = 16; o > 0; o >>= 1) m = fmaxf(m, __shfl_xor(m, o, 32));
  float e = __expf(logit - m);
  float s = e;
#pragma unroll
  for (int o = 16; o > 0; o >>= 1) s += __shfl_xor(s, o, 32);
  const float a = e / s;
  __syncthreads();

  {
    const int h1 = t >> 5, lp = t & 31, lvl = lp >> 3, p = lp & 7, z = p & 3;
    const int WW = 160 >> lvl;
    const int HH = (lvl < 3) ? (92 >> lvl) : 12;
    const int S  = (lvl == 0) ? 0 : (lvl == 1) ? 14720 : (lvl == 2) ? 18400 : 19320;
    const float Wf = (float)WW, Hf = (float)HH;
    const float ox = s_off[h1 * 64 + lp * 2];
    const float oy = s_off[h1 * 64 + lp * 2 + 1];
#pragma unroll 1
    for (int cam = 0; cam < NCAMS; ++cam) {
      if (!s_valid[cam]) continue;
      float rx = s_ref[cam * 8 + z * 2];
      float ry = s_ref[cam * 8 + z * 2 + 1];
      float x = rx * Wf + ox - 0.5f;
      float y = ry * Hf + oy - 0.5f;
      float x0f = floorf(x), y0f = floorf(y);
      float fx = x - x0f, fy = y - y0f;
      int x0 = (int)x0f, y0 = (int)y0f;
      int base = cam * LTOT + S;
#pragma unroll
      for (int dy = 0; dy < 2; ++dy) {
        int yi = y0 + dy;
        float wy = dy ? fy : 1.f - fy;
        int yc = min(max(yi, 0), HH - 1);
        bool vy = (yi >= 0) && (yi < HH);
#pragma unroll
        for (int dx = 0; dx < 2; ++dx) {
          int xi = x0 + dx;
          float wx = dx ? fx : 1.f - fx;
          int xc = min(max(xi, 0), WW - 1);
          bool vv = vy && (xi >= 0) && (xi < WW);
          float wgt = vv ? wx * wy * a : 0.f;
          int addr = (base + yc * WW + xc) * 512;
          s_pack[dy * 2 + dx][cam][t] = make_int2(addr, __float_as_int(wgt));
        }
      }
    }
  }
  __syncthreads();

  const int h = t >> 5, pp = (t >> 3) & 3, l8 = t & 7;
  const unsigned dconst = (unsigned)(h * 64 + l8 * 8);
  const char* vb = (const char*)val;
  int nvalid = s_valid[0] + s_valid[1] + s_valid[2] + s_valid[3] + s_valid[4] + s_valid[5];
  float inv = 1.f / fmaxf((float)nvalid, 1.f);

  f32x4 acc = {0.f, 0.f, 0.f, 0.f};
#pragma unroll 1
  for (int cam = 0; cam < NCAMS; ++cam) {
    if (!s_valid[cam]) continue;
#pragma unroll
    for (int it = 0; it < 8; ++it) {
      const int idx = h * 32 + pp + it * 4;
      int2 pk0 = s_pack[0][cam][idx];
      int2 pk1 = s_pack[1][cam][idx];
      int2 pk2 = s_pack[2][cam][idx];
      int2 pk3 = s_pack[3][cam][idx];
      uint2 v0 = *(const uint2*)(vb + (size_t)((unsigned)pk0.x + dconst));
      uint2 v1 = *(const uint2*)(vb + (size_t)((unsigned)pk1.x + dconst));
      uint2 v2 = *(const uint2*)(vb + (size_t)((unsigned)pk2.x + dconst));
      uint2 v3 = *(const uint2*)(vb + (size_t)((unsigned)pk3.x + dconst));
      float w0 = __int_as_float(pk0.y), w1 = __int_as_float(pk1.y);
      float w2 = __int_as_float(pk2.y), w3 = __int_as_float(pk3.y);
      acc[0] += w0 * __uint_as_float(v0.x << 16);
      acc[1] += w0 * __uint_as_float(v0.x & 0xffff0000u);
      acc[2] += w0 * __uint_as_float(v0.y << 16);
      acc[3] += w0 * __uint_as_float(v0.y & 0xffff0000u);
      acc[0] += w1 * __uint_as_float(v1.x << 16);
      acc[1] += w1 * __uint_as_float(v1.x & 0xffff0000u);
      acc[2] += w1 * __uint_as_float(v1.y << 16);
      acc[3] += w1 * __uint_as_float(v1.y & 0xffff0000u);
      acc[0] += w2 * __uint_as_float(v2.x << 16);
      acc[1] += w2 * __uint_as_float(v2.x & 0xffff0000u);
      acc[2] += w2 * __uint_as_float(v2.y << 16);
      acc[3] += w2 * __uint_as_float(v2.y & 0xffff0000u);
      acc[0] += w3 * __uint_as_float(v3.x << 16);
      acc[1] += w3 * __uint_as_float(v3.x & 0xffff0000u);
      acc[2] += w3 * __uint_as_float(v3.y << 16);
      acc[3] += w3 * __uint_as_float(v3.y & 0xffff0000u);
    }
  }

#pragma unroll
  for (int i = 0; i < 4; ++i) {
    acc[i] += __shfl_xor(acc[i], 8);
    acc[i] += __shfl_xor(acc[i], 16);
  }
  if (pp == 0) {
    uint2 r;
    r.x = (unsigned)f2bf(acc[0] * inv) | ((unsigned)f2bf(acc[1] * inv) << 16);
    r.y = (unsigned)f2bf(acc[2] * inv) | ((unsigned)f2bf(acc[3] * inv) << 16);
    *(uint2*)&slots[(size_t)q * 256 + h * 32 + l8 * 4] = r;
  }
}

// ---------------------------------------------------------------------------
extern "C" void kernel_launch(void* const* d_in, const int* in_sizes, int n_in,
                              void* d_out, int out_size, void* d_ws, size_t ws_size,
                              hipStream_t stream) {
  const float* query     = (const float*)d_in[0];
  const float* key_feats = (const float*)d_in[1];
  const float* ref       = (const float*)d_in[2];
  const unsigned char* mask = (const unsigned char*)d_in[3];
  // d_in[4] = spatial_shapes (compile-time constants)
  const float* Wv    = (const float*)d_in[5];
  const float* bv    = (const float*)d_in[6];
  const float* Woff  = (const float*)d_in[7];
  const float* boff  = (const float*)d_in[8];
  const float* Wattn = (const float*)d_in[9];
  const float* battn = (const float*)d_in[10];
  const float* Wout  = (const float*)d_in[11];
  const float* bout  = (const float*)d_in[12];
  float* out = (float*)d_out;

  char* ws = (char*)d_ws;
  size_t off = 0;
  unsigned short* val   = (unsigned short*)(ws + off); off += (size_t)MVAL * 256 * 2;
  unsigned short* WT    = (unsigned short*)(ws + off); off += 256 * 256 * 2;
  unsigned short* WTq   = (unsigned short*)(ws + off); off += 768 * 256 * 2;
  unsigned short* WoutT = (unsigned short*)(ws + off); off += 256 * 256 * 2;
  unsigned short* qbf   = (unsigned short*)(ws + off); off += (size_t)NQ * 256 * 2;
  float* OFFLOG = (float*)(ws + off); off += (size_t)NQ * 768 * 4;
  unsigned short* slots = (unsigned short*)(ws + off); off += (size_t)NQ * 256 * 2;
  unsigned char* valid  = (unsigned char*)(ws + off); off += NCAMS * NQ;

  const int MASKBLKS = (NCAMS * NQ + 255) / 256;  // 59
  hipLaunchKernelGGL(k_prep, dim3(1280 + NQ + MASKBLKS), dim3(256), 0, stream,
                     Wv, Woff, Wattn, Wout, query, mask, WT, WTq, WoutT, qbf, valid);
  hipLaunchKernelGGL(k_valproj, dim3((MVAL + 63) / 64), dim3(512), 0, stream,
                     key_feats, WT, bv, val);
  hipLaunchKernelGGL(k_gemm_small, dim3((NQ + 127) / 128, 6), dim3(256), 0, stream,
                     qbf, WTq, boff, battn, 512, (const float*)nullptr, OFFLOG, NQ, 768, 0);
  hipLaunchKernelGGL(k_sample, dim3(NQ), dim3(256), 0, stream,
                     val, OFFLOG, ref, valid, slots);
  hipLaunchKernelGGL(k_gemm_small, dim3((NQ + 127) / 128, 2), dim3(256), 0, stream,
                     slots, WoutT, bout, bout, 1 << 30, query, out, NQ, 256, 1);
}

// Round 14
// 136.657 us; speedup vs baseline: 3.0218x; 1.0577x over previous
//
#include <hip/hip_runtime.h>
#include <hip/hip_bf16.h>
#include <cstdint>

#define NCAMS 6
#define NQ 2500
#define EMBED 256
#define HEADS 8
#define DHEAD 32
#define LTOT 19560
#define MVAL (NCAMS * LTOT) /* 117360 */

typedef __attribute__((ext_vector_type(8))) short bf16x8;
typedef __attribute__((ext_vector_type(4))) float f32x4;

__device__ __forceinline__ unsigned short f2bf(float f) {
  unsigned u = __float_as_uint(f);
  return (unsigned short)((u + 0x7fffu + ((u >> 16) & 1u)) >> 16);
}
__device__ __forceinline__ unsigned short bfbits(float x) {
  __hip_bfloat16 h = __float2bfloat16(x);
  return __builtin_bit_cast(unsigned short, h);
}
__device__ __forceinline__ void gl16(const void* g, void* l) {
  __builtin_amdgcn_global_load_lds(
      (const __attribute__((address_space(1))) unsigned int*)g,
      (__attribute__((address_space(3))) unsigned int*)l, 16, 0, 0);
}

// ---------------------------------------------------------------------------
// Kernel P: weight transposes -> bf16, query -> bf16, AND bev_mask -> valid.
// ---------------------------------------------------------------------------
__global__ __launch_bounds__(256) void k_prep(
    const float* __restrict__ Wv, const float* __restrict__ Woff,
    const float* __restrict__ Wattn, const float* __restrict__ Wout,
    const float* __restrict__ query, const unsigned char* __restrict__ MSK,
    unsigned short* __restrict__ WT, unsigned short* __restrict__ WTq,
    unsigned short* __restrict__ WoutT, unsigned short* __restrict__ qbf,
    unsigned char* __restrict__ valid)
{
  const int b = blockIdx.x, t = threadIdx.x;
  if (b < 256) {
    WT[(size_t)b * 256 + t] = f2bf(Wv[(size_t)t * 256 + b]);
  } else if (b < 768) {
    int c = b - 256;
    WTq[(size_t)c * 256 + t] = f2bf(Woff[(size_t)t * 512 + c]);
  } else if (b < 1024) {
    int c = b - 768;
    WTq[(size_t)(512 + c) * 256 + t] = f2bf(Wattn[(size_t)t * 256 + c]);
  } else if (b < 1280) {
    int c = b - 1024;
    WoutT[(size_t)c * 256 + t] = f2bf(Wout[(size_t)t * 256 + c]);
  } else if (b < 1280 + NQ) {
    int q = b - 1280;
    qbf[(size_t)q * 256 + t] = f2bf(query[(size_t)q * 256 + t]);
  } else {
    __shared__ int s_u8;
    if (t == 0) s_u8 = 0;
    __syncthreads();
    if ((t & 3) && MSK[t]) atomicOr(&s_u8, 1);
    __syncthreads();
    const int isU8 = s_u8;
    const int i = (b - 1280 - NQ) * 256 + t;
    if (i < NCAMS * NQ) {
      int any;
      if (isU8) {
        const unsigned char* p = MSK + (size_t)i * 4;
        any = p[0] | p[1] | p[2] | p[3];
      } else {
        const int* p = (const int*)MSK + (size_t)i * 4;
        any = p[0] | p[1] | p[2] | p[3];
      }
      valid[i] = any ? 1 : 0;
    }
  }
}

// ---------------------------------------------------------------------------
// Kernel A (v9): val = bf16( A_f32 @ W_value + b_value )   (unchanged r13)
// ---------------------------------------------------------------------------
__global__ __launch_bounds__(512, 4) void k_valproj(
    const float* __restrict__ A,            // (117360, 256) f32
    const unsigned short* __restrict__ WT,  // (256 cols, 256 k) bf16
    const float* __restrict__ bv,           // (256,)
    unsigned short* __restrict__ val)       // (117360, 256) bf16
{
  __shared__ unsigned int smemu[12288];                 // 48 KB
  float* Af = (float*)smemu;                            // [64][64] f32 (swizzled)
  unsigned short* Bs = (unsigned short*)(smemu + 4096); // [256][64] bf16 (swizzled)
  const int t = threadIdx.x;
  const int lane = t & 63;
  const int wid = t >> 6;
  const int wm = wid >> 2, wn = wid & 3;
  const int laneM = lane & 15, kGrp = lane >> 4;
  const int b3 = (laneM >> 3) & 1;
  const int bm = blockIdx.x * 64;

  const float* aS[2];
#pragma unroll
  for (int p = 0; p < 2; ++p) {
    int g16 = (wid * 2 + p) * 64 + lane;
    int row = g16 >> 4;
    int gl  = g16 & 15;
    int g   = gl ^ (((row & 7) << 1) | ((row >> 3) & 1));
    aS[p] = A + (size_t)min(bm + row, MVAL - 1) * 256 + g * 4;
  }
  const int sub = t >> 3;
  const int swz = (t & 7) ^ (sub & 7);
  const unsigned short* bS[4];
#pragma unroll
  for (int p = 0; p < 4; ++p)
    bS[p] = WT + (size_t)(p * 64 + sub) * 256 + swz * 8;

  f32x4 acc[2][4];
#pragma unroll
  for (int m = 0; m < 2; ++m)
#pragma unroll
    for (int n = 0; n < 4; ++n) acc[m][n] = {0.f, 0.f, 0.f, 0.f};

#pragma unroll 1
  for (int kk = 0; kk < 4; ++kk) {
    if (kk) __syncthreads();
    const int koF = kk * 64;
#pragma unroll
    for (int p = 0; p < 2; ++p)
      gl16(aS[p] + koF, Af + (wid * 2 + p) * 256);
#pragma unroll
    for (int p = 0; p < 4; ++p)
      gl16(bS[p] + koF, Bs + p * 4096 + wid * 512);
    __syncthreads();

#pragma unroll
    for (int ks = 0; ks < 2; ++ks) {
      bf16x8 af[2], bfr[4];
#pragma unroll
      for (int m = 0; m < 2; ++m) {
        int row = wm * 32 + m * 16 + laneM;
        int u = (ks * 4 + kGrp) ^ (row & 7);
        const float* p8 = &Af[row * 64 + u * 8];
        float4 x = *(const float4*)(p8 + b3 * 4);
        float4 y = *(const float4*)(p8 + 4 - b3 * 4);
        union { bf16x8 v; unsigned short u16[8]; } c;
        c.u16[0] = bfbits(x.x); c.u16[1] = bfbits(x.y);
        c.u16[2] = bfbits(x.z); c.u16[3] = bfbits(x.w);
        c.u16[4] = bfbits(y.x); c.u16[5] = bfbits(y.y);
        c.u16[6] = bfbits(y.z); c.u16[7] = bfbits(y.w);
        af[m] = c.v;
      }
#pragma unroll
      for (int n = 0; n < 4; ++n) {
        int row = wn * 64 + n * 16 + laneM;
        bfr[n] = *(bf16x8*)&Bs[row * 64 + (((ks * 4 + kGrp) ^ (row & 7)) << 3)];
      }
#pragma unroll
      for (int m = 0; m < 2; ++m)
#pragma unroll
        for (int n = 0; n < 4; ++n)
          acc[m][n] = __builtin_amdgcn_mfma_f32_16x16x32_bf16(bfr[n], af[m], acc[m][n], 0, 0, 0);
    }
  }

  float4 bb4[4];
#pragma unroll
  for (int n = 0; n < 4; ++n)
    bb4[n] = *(const float4*)&bv[wn * 64 + n * 16 + kGrp * 4];

  __syncthreads();
  unsigned short* tlw = (unsigned short*)smemu + wid * (32 * 72);

#pragma unroll
  for (int m = 0; m < 2; ++m) {
#pragma unroll
    for (int n = 0; n < 4; ++n) {
      uint2 u;
      u.x = (unsigned)bfbits(acc[m][n][0] + bb4[n].x) |
            ((unsigned)bfbits(acc[m][n][1] + bb4[n].y) << 16);
      u.y = (unsigned)bfbits(acc[m][n][2] + bb4[n].z) |
            ((unsigned)bfbits(acc[m][n][3] + bb4[n].w) << 16);
      *(uint2*)&tlw[(m * 16 + laneM) * 72 + n * 16 + kGrp * 4] = u;
    }
  }
#pragma unroll
  for (int i = 0; i < 4; ++i) {
    const int rowl = i * 8 + (lane >> 3);
    const int c8 = lane & 7;
    uint4 v = *(const uint4*)&tlw[rowl * 72 + c8 * 8];
    const int row = bm + wm * 32 + rowl;
    if (row < MVAL)
      *(uint4*)&val[(size_t)row * 256 + wn * 64 + c8 * 8] = v;
  }
}

// ---------------------------------------------------------------------------
// Kernel G: generic small-M GEMM.  C(M,N) = A_bf16(M,256) @ BT_bf16(N,256)^T
// ---------------------------------------------------------------------------
__global__ __launch_bounds__(256, 2) void k_gemm_small(
    const unsigned short* __restrict__ A,
    const unsigned short* __restrict__ BT,
    const float* __restrict__ ba, const float* __restrict__ bb, int bsplit,
    const float* __restrict__ resid,
    float* __restrict__ C, int M, int N, int withResid)
{
  __shared__ unsigned short As[128 * 64];
  __shared__ unsigned short Bs[128 * 64];
  const int t = threadIdx.x;
  const int lane = t & 63;
  const int wid = t >> 6;
  const int wm = wid >> 1, wn = wid & 1;
  const int laneM = lane & 15, kGrp = lane >> 4;
  const int bm = blockIdx.x * 128;
  const int bn = blockIdx.y * 128;

  const int aC = t & 7, aR0 = t >> 3;

  uint4 aRegs[2][4];
  uint4 bRegs[2][4];
  f32x4 acc[4][4];
#pragma unroll
  for (int m = 0; m < 4; ++m)
#pragma unroll
    for (int n = 0; n < 4; ++n) acc[m][n] = {0.f, 0.f, 0.f, 0.f};

#pragma unroll
  for (int p = 0; p < 4; ++p) {
    int arow = bm + aR0 + p * 32;
    aRegs[0][p] = (arow < M) ? *(const uint4*)&A[(size_t)arow * 256 + aC * 8]
                             : make_uint4(0u, 0u, 0u, 0u);
    bRegs[0][p] = *(const uint4*)&BT[(size_t)(bn + aR0 + p * 32) * 256 + aC * 8];
  }

#pragma unroll
  for (int kk = 0; kk < 4; ++kk) {
    const int cur = kk & 1, nxt = cur ^ 1;
    if (kk) __syncthreads();
#pragma unroll
    for (int p = 0; p < 4; ++p) {
      int row = aR0 + p * 32;
      int elem = row * 64 + ((aC ^ (row & 7)) << 3);
      *(uint4*)&As[elem] = aRegs[cur][p];
      *(uint4*)&Bs[elem] = bRegs[cur][p];
    }
    __syncthreads();
    if (kk < 3) {
      const int kn = (kk + 1) * 64;
#pragma unroll
      for (int p = 0; p < 4; ++p) {
        int arow = bm + aR0 + p * 32;
        aRegs[nxt][p] = (arow < M)
            ? *(const uint4*)&A[(size_t)arow * 256 + kn + aC * 8]
            : make_uint4(0u, 0u, 0u, 0u);
        bRegs[nxt][p] = *(const uint4*)&BT[(size_t)(bn + aR0 + p * 32) * 256 + kn + aC * 8];
      }
    }
#pragma unroll
    for (int ks = 0; ks < 2; ++ks) {
      bf16x8 af[4], bfr[4];
#pragma unroll
      for (int m = 0; m < 4; ++m) {
        int row = wm * 64 + m * 16 + laneM;
        af[m] = *(bf16x8*)&As[row * 64 + (((ks * 4 + kGrp) ^ (row & 7)) << 3)];
      }
#pragma unroll
      for (int n = 0; n < 4; ++n) {
        int row = wn * 64 + n * 16 + laneM;
        bfr[n] = *(bf16x8*)&Bs[row * 64 + (((ks * 4 + kGrp) ^ (row & 7)) << 3)];
      }
#pragma unroll
      for (int m = 0; m < 4; ++m)
#pragma unroll
        for (int n = 0; n < 4; ++n)
          acc[m][n] = __builtin_amdgcn_mfma_f32_16x16x32_bf16(af[m], bfr[n], acc[m][n], 0, 0, 0);
    }
  }

  float bvn[4];
#pragma unroll
  for (int n = 0; n < 4; ++n) {
    int col = bn + wn * 64 + n * 16 + laneM;
    bvn[n] = (col < bsplit) ? ba[col] : bb[col - bsplit];
  }
#pragma unroll
  for (int m = 0; m < 4; ++m) {
#pragma unroll
    for (int r = 0; r < 4; ++r) {
      int row = bm + wm * 64 + m * 16 + kGrp * 4 + r;
      if (row < M) {
#pragma unroll
        for (int n = 0; n < 4; ++n) {
          int col = bn + wn * 64 + n * 16 + laneM;
          float v = acc[m][n][r] + bvn[n];
          if (withResid) v += resid[(size_t)row * 256 + col];
          C[(size_t)row * N + col] = v;
        }
      }
    }
  }
}

// ---------------------------------------------------------------------------
// Kernel C (v3): two-phase sampling with uint4 gathers.
// Phase 1 unchanged: tuple t = h*32 + lvl*8 + p computes 4 corner packs/cam.
// Phase 2 remap: h = t>>5, pp = (t>>2)&7 (point slot), l4 = t&3 (d-oct,
// 16B = 8 d's). Iteration it = level; point (lvl=it, p=pp). 4-lane groups
// read 64B val rows contiguously; loads per cam halved vs uint2 variant.
// Reduce over pp (shfl_xor 4,8,16); pp==0 stores uint4 to slots.
// ---------------------------------------------------------------------------
__global__ __launch_bounds__(256) void k_sample(
    const unsigned short* __restrict__ val,   // (117360, 256) bf16
    const float* __restrict__ OFFLOG,         // (2500, 768)
    const float* __restrict__ REF,            // (6,1,2500,4,2)
    const unsigned char* __restrict__ valid,  // (6,2500)
    unsigned short* __restrict__ slots)       // (2500,256) bf16
{
  __shared__ int2  s_pack[4][NCAMS][256];
  __shared__ float s_off[512];
  __shared__ float s_ref[48];
  __shared__ int   s_valid[6];

  const int q = blockIdx.x;
  const int t = threadIdx.x;

  s_off[t]       = OFFLOG[(size_t)q * 768 + t];
  s_off[t + 256] = OFFLOG[(size_t)q * 768 + 256 + t];
  if (t < 48) s_ref[t] = REF[(size_t)(t >> 3) * (NQ * 8) + (size_t)q * 8 + (t & 7)];
  if (t < 6) s_valid[t] = valid[(size_t)t * NQ + q];

  float logit = OFFLOG[(size_t)q * 768 + 512 + t];
  float m = logit;
#pragma unroll
  for (int o = 16; o > 0; o >>= 1) m = fmaxf(m, __shfl_xor(m, o, 32));
  float e = __expf(logit - m);
  float s = e;
#pragma unroll
  for (int o = 16; o > 0; o >>= 1) s += __shfl_xor(s, o, 32);
  const float a = e / s;
  __syncthreads();

  // ---- phase 1: per-tuple corner addresses & weights (unchanged) ----
  {
    const int h1 = t >> 5, lp = t & 31, lvl = lp >> 3, p = lp & 7, z = p & 3;
    const int WW = 160 >> lvl;
    const int HH = (lvl < 3) ? (92 >> lvl) : 12;
    const int S  = (lvl == 0) ? 0 : (lvl == 1) ? 14720 : (lvl == 2) ? 18400 : 19320;
    const float Wf = (float)WW, Hf = (float)HH;
    const float ox = s_off[h1 * 64 + lp * 2];
    const float oy = s_off[h1 * 64 + lp * 2 + 1];
#pragma unroll 1
    for (int cam = 0; cam < NCAMS; ++cam) {
      if (!s_valid[cam]) continue;
      float rx = s_ref[cam * 8 + z * 2];
      float ry = s_ref[cam * 8 + z * 2 + 1];
      float x = rx * Wf + ox - 0.5f;
      float y = ry * Hf + oy - 0.5f;
      float x0f = floorf(x), y0f = floorf(y);
      float fx = x - x0f, fy = y - y0f;
      int x0 = (int)x0f, y0 = (int)y0f;
      int base = cam * LTOT + S;
#pragma unroll
      for (int dy = 0; dy < 2; ++dy) {
        int yi = y0 + dy;
        float wy = dy ? fy : 1.f - fy;
        int yc = min(max(yi, 0), HH - 1);
        bool vy = (yi >= 0) && (yi < HH);
#pragma unroll
        for (int dx = 0; dx < 2; ++dx) {
          int xi = x0 + dx;
          float wx = dx ? fx : 1.f - fx;
          int xc = min(max(xi, 0), WW - 1);
          bool vv = vy && (xi >= 0) && (xi < WW);
          float wgt = vv ? wx * wy * a : 0.f;
          int addr = (base + yc * WW + xc) * 512;
          s_pack[dy * 2 + dx][cam][t] = make_int2(addr, __float_as_int(wgt));
        }
      }
    }
  }
  __syncthreads();

  // ---- phase 2: uint4 gathers (8 d's per lane) ----
  const int h = t >> 5, pp = (t >> 2) & 7, l4 = t & 3;
  const unsigned dconst = (unsigned)(h * 64 + l4 * 16);
  const char* vb = (const char*)val;
  int nvalid = s_valid[0] + s_valid[1] + s_valid[2] + s_valid[3] + s_valid[4] + s_valid[5];
  float inv = 1.f / fmaxf((float)nvalid, 1.f);

  float a0 = 0.f, a1 = 0.f, a2 = 0.f, a3 = 0.f;
  float a4 = 0.f, a5 = 0.f, a6 = 0.f, a7 = 0.f;
#pragma unroll 1
  for (int cam = 0; cam < NCAMS; ++cam) {
    if (!s_valid[cam]) continue;
#pragma unroll
    for (int it = 0; it < 4; ++it) {
      const int idx = h * 32 + it * 8 + pp;
      int2 pk0 = s_pack[0][cam][idx];
      int2 pk1 = s_pack[1][cam][idx];
      int2 pk2 = s_pack[2][cam][idx];
      int2 pk3 = s_pack[3][cam][idx];
      uint4 v0 = *(const uint4*)(vb + (size_t)((unsigned)pk0.x + dconst));
      uint4 v1 = *(const uint4*)(vb + (size_t)((unsigned)pk1.x + dconst));
      uint4 v2 = *(const uint4*)(vb + (size_t)((unsigned)pk2.x + dconst));
      uint4 v3 = *(const uint4*)(vb + (size_t)((unsigned)pk3.x + dconst));
      float w0 = __int_as_float(pk0.y), w1 = __int_as_float(pk1.y);
      float w2 = __int_as_float(pk2.y), w3 = __int_as_float(pk3.y);
      a0 += w0 * __uint_as_float(v0.x << 16);
      a1 += w0 * __uint_as_float(v0.x & 0xffff0000u);
      a2 += w0 * __uint_as_float(v0.y << 16);
      a3 += w0 * __uint_as_float(v0.y & 0xffff0000u);
      a4 += w0 * __uint_as_float(v0.z << 16);
      a5 += w0 * __uint_as_float(v0.z & 0xffff0000u);
      a6 += w0 * __uint_as_float(v0.w << 16);
      a7 += w0 * __uint_as_float(v0.w & 0xffff0000u);
      a0 += w1 * __uint_as_float(v1.x << 16);
      a1 += w1 * __uint_as_float(v1.x & 0xffff0000u);
      a2 += w1 * __uint_as_float(v1.y << 16);
      a3 += w1 * __uint_as_float(v1.y & 0xffff0000u);
      a4 += w1 * __uint_as_float(v1.z << 16);
      a5 += w1 * __uint_as_float(v1.z & 0xffff0000u);
      a6 += w1 * __uint_as_float(v1.w << 16);
      a7 += w1 * __uint_as_float(v1.w & 0xffff0000u);
      a0 += w2 * __uint_as_float(v2.x << 16);
      a1 += w2 * __uint_as_float(v2.x & 0xffff0000u);
      a2 += w2 * __uint_as_float(v2.y << 16);
      a3 += w2 * __uint_as_float(v2.y & 0xffff0000u);
      a4 += w2 * __uint_as_float(v2.z << 16);
      a5 += w2 * __uint_as_float(v2.z & 0xffff0000u);
      a6 += w2 * __uint_as_float(v2.w << 16);
      a7 += w2 * __uint_as_float(v2.w & 0xffff0000u);
      a0 += w3 * __uint_as_float(v3.x << 16);
      a1 += w3 * __uint_as_float(v3.x & 0xffff0000u);
      a2 += w3 * __uint_as_float(v3.y << 16);
      a3 += w3 * __uint_as_float(v3.y & 0xffff0000u);
      a4 += w3 * __uint_as_float(v3.z << 16);
      a5 += w3 * __uint_as_float(v3.z & 0xffff0000u);
      a6 += w3 * __uint_as_float(v3.w << 16);
      a7 += w3 * __uint_as_float(v3.w & 0xffff0000u);
    }
  }

  // reduce over pp (lane bits 2,3,4)
#pragma unroll
  for (int o = 4; o <= 16; o <<= 1) {
    a0 += __shfl_xor(a0, o); a1 += __shfl_xor(a1, o);
    a2 += __shfl_xor(a2, o); a3 += __shfl_xor(a3, o);
    a4 += __shfl_xor(a4, o); a5 += __shfl_xor(a5, o);
    a6 += __shfl_xor(a6, o); a7 += __shfl_xor(a7, o);
  }
  if (pp == 0) {
    uint4 r;
    r.x = (unsigned)f2bf(a0 * inv) | ((unsigned)f2bf(a1 * inv) << 16);
    r.y = (unsigned)f2bf(a2 * inv) | ((unsigned)f2bf(a3 * inv) << 16);
    r.z = (unsigned)f2bf(a4 * inv) | ((unsigned)f2bf(a5 * inv) << 16);
    r.w = (unsigned)f2bf(a6 * inv) | ((unsigned)f2bf(a7 * inv) << 16);
    *(uint4*)&slots[(size_t)q * 256 + h * 32 + l4 * 8] = r;
  }
}

// ---------------------------------------------------------------------------
extern "C" void kernel_launch(void* const* d_in, const int* in_sizes, int n_in,
                              void* d_out, int out_size, void* d_ws, size_t ws_size,
                              hipStream_t stream) {
  const float* query     = (const float*)d_in[0];
  const float* key_feats = (const float*)d_in[1];
  const float* ref       = (const float*)d_in[2];
  const unsigned char* mask = (const unsigned char*)d_in[3];
  // d_in[4] = spatial_shapes (compile-time constants)
  const float* Wv    = (const float*)d_in[5];
  const float* bv    = (const float*)d_in[6];
  const float* Woff  = (const float*)d_in[7];
  const float* boff  = (const float*)d_in[8];
  const float* Wattn = (const float*)d_in[9];
  const float* battn = (const float*)d_in[10];
  const float* Wout  = (const float*)d_in[11];
  const float* bout  = (const float*)d_in[12];
  float* out = (float*)d_out;

  char* ws = (char*)d_ws;
  size_t off = 0;
  unsigned short* val   = (unsigned short*)(ws + off); off += (size_t)MVAL * 256 * 2;
  unsigned short* WT    = (unsigned short*)(ws + off); off += 256 * 256 * 2;
  unsigned short* WTq   = (unsigned short*)(ws + off); off += 768 * 256 * 2;
  unsigned short* WoutT = (unsigned short*)(ws + off); off += 256 * 256 * 2;
  unsigned short* qbf   = (unsigned short*)(ws + off); off += (size_t)NQ * 256 * 2;
  float* OFFLOG = (float*)(ws + off); off += (size_t)NQ * 768 * 4;
  unsigned short* slots = (unsigned short*)(ws + off); off += (size_t)NQ * 256 * 2;
  unsigned char* valid  = (unsigned char*)(ws + off); off += NCAMS * NQ;

  const int MASKBLKS = (NCAMS * NQ + 255) / 256;  // 59
  hipLaunchKernelGGL(k_prep, dim3(1280 + NQ + MASKBLKS), dim3(256), 0, stream,
                     Wv, Woff, Wattn, Wout, query, mask, WT, WTq, WoutT, qbf, valid);
  hipLaunchKernelGGL(k_valproj, dim3((MVAL + 63) / 64), dim3(512), 0, stream,
                     key_feats, WT, bv, val);
  hipLaunchKernelGGL(k_gemm_small, dim3((NQ + 127) / 128, 6), dim3(256), 0, stream,
                     qbf, WTq, boff, battn, 512, (const float*)nullptr, OFFLOG, NQ, 768, 0);
  hipLaunchKernelGGL(k_sample, dim3(NQ), dim3(256), 0, stream,
                     val, OFFLOG, ref, valid, slots);
  hipLaunchKernelGGL(k_gemm_small, dim3((NQ + 127) / 128, 2), dim3(256), 0, stream,
                     slots, WoutT, bout, bout, 1 << 30, query, out, NQ, 256, 1);
}